// Round 5
// baseline (316.765 us; speedup 1.0000x reference)
//
#include <hip/hip_runtime.h>
#include <hip/hip_fp16.h>
#include <math.h>

#define NRAY 8192
#define NC_  48
#define NI_  48
#define HPL  256
#define HID  64
#define NPTS (NRAY * NC_)        // 393216 points per pass
#define BPTS 96                  // points per block = EXACTLY 2 rays (ray-aligned)

typedef __attribute__((ext_vector_type(8))) _Float16 half8;  // 8 fp16 (4 VGPRs)
typedef __attribute__((ext_vector_type(4))) float f32x4;

__device__ __forceinline__ float softplusf(float x) {
    return fmaxf(x, 0.0f) + __logf(1.0f + __expf(-fabsf(x)));
}
__device__ __forceinline__ float sigmoidf(float x) {
    return 1.0f / (1.0f + __expf(-x));
}

// ================= setup mega-kernel =================
// blocks [0, 3072): transpose (p in [0,12), y in [0,256)) -> fp16 channel-last interleaved.
// block 3072: weight fragment prep (fp16 W1 fragments).
// blocks 3073..3088: minmax partials from noise (no atomics).
// blocks 3089..3120: per-ray dir normalization -> rayod[ray*8] = {ox,oy,oz,dx,dy,dz,0,0}
#define TR_BLOCKS 3072
__global__ __launch_bounds__(256) void setup_kernel(
    const float* __restrict__ tex, const float* __restrict__ shp,
    __half* __restrict__ planes_cl,
    const float* __restrict__ W1, const float* __restrict__ b1, const float* __restrict__ W2,
    __half* __restrict__ w1f, float* __restrict__ w2f, float* __restrict__ b1f,
    float* __restrict__ part_mn, float* __restrict__ part_mx,
    const float* __restrict__ noise,
    const float* __restrict__ origins, const float* __restrict__ dirs,
    float* __restrict__ rayod)
{
    __shared__ __half t2[256][40];     // [x][c]; 16B-aligned rows, 2-way write conflict only
    __shared__ float smn[4], smx[4];
    int b = blockIdx.x;
    int tid = threadIdx.x;
    if (b < TR_BLOCKS) {
        int p = b >> 8;                // [0,12)
        int y = b & 255;
        const float* in = (p < 6) ? tex : shp;
        int pp    = (p < 6) ? p : p - 6;
        int choff = (p < 6) ? 0 : 32;
        const float* base = in + ((size_t)(pp * 32) * 256 + y) * 256;   // base[c*65536 + x]
        int lane6 = tid & 63;          // x-group within wave
        int cb    = (tid >> 6) * 8;    // c base: 0,8,16,24 per wave
        int x0    = lane6 * 4;
#pragma unroll
        for (int i = 0; i < 8; ++i) {
            float4 v = *(const float4*)(base + (size_t)(cb + i) * 65536 + x0);
            t2[x0 + 0][cb + i] = __float2half(v.x);
            t2[x0 + 1][cb + i] = __float2half(v.y);
            t2[x0 + 2][cb + i] = __float2half(v.z);
            t2[x0 + 3][cb + i] = __float2half(v.w);
        }
        __syncthreads();
        __half* outRow = planes_cl + ((size_t)(pp * 256 + y) * 256) * 64 + choff;
#pragma unroll
        for (int it = 0; it < 4; ++it) {
            int idx = it * 256 + tid;
            int x = idx >> 2, c8 = (idx & 3) * 8;
            *(uint4*)(outRow + (size_t)x * 64 + c8) = *(const uint4*)&t2[x][c8];
        }
    } else if (b == TR_BLOCKS) {
        int l = tid;
        if (l < 64) {
            int g = l >> 4, c = l & 15;
#pragma unroll
            for (int t = 0; t < 4; ++t) {
#pragma unroll
                for (int kb = 0; kb < 2; ++kb)
#pragma unroll
                    for (int j = 0; j < 8; ++j)
                        w1f[((t * 2 + kb) * 64 + l) * 8 + j] =
                            __float2half(W1[(kb * 32 + g * 8 + j) * HID + t * 16 + c]);
#pragma unroll
                for (int o = 0; o < 4; ++o) w2f[(t * 64 + l) * 4 + o] = W2[(t * 16 + c) * 4 + o];
                b1f[t * 64 + l] = b1[t * 16 + c];
            }
        }
    } else if (b < TR_BLOCKS + 17) {
        // minmax partials
        int bl = b - TR_BLOCKS - 1;            // [0,16)
        int gtid = bl * 256 + tid;             // [0,4096)
        float mn = INFINITY, mx = -INFINITY;
        for (int r = gtid; r < NRAY; r += 4096) {
            mn = fminf(mn, noise[r * NC_]);
            mx = fmaxf(mx, noise[r * NC_ + NC_ - 1]);
        }
#pragma unroll
        for (int mask = 1; mask <= 32; mask <<= 1) {
            mn = fminf(mn, __shfl_xor(mn, mask, 64));
            mx = fmaxf(mx, __shfl_xor(mx, mask, 64));
        }
        int wv = tid >> 6;
        if ((tid & 63) == 0) { smn[wv] = mn; smx[wv] = mx; }
        __syncthreads();
        if (tid == 0) {
#pragma unroll
            for (int i = 1; i < 4; ++i) { mn = fminf(mn, smn[i]); mx = fmaxf(mx, smx[i]); }
            const float delta = (1.0f - 0.1f) / (NC_ - 1);
            part_mn[bl] = 0.1f + mn * delta;                    // s = 0 term
            part_mx[bl] = 0.1f + delta * 47.0f + mx * delta;    // s = 47 term
        }
    } else {
        // per-ray normalized direction precompute
        int ray = (b - TR_BLOCKS - 17) * 256 + tid;             // [0,8192)
        float ox = origins[ray * 3 + 0], oy = origins[ray * 3 + 1], oz = origins[ray * 3 + 2];
        float dx = dirs[ray * 3 + 0], dy = dirs[ray * 3 + 1], dz = dirs[ray * 3 + 2];
        float invn = 1.0f / sqrtf(dx * dx + dy * dy + dz * dz);
        dx *= invn; dy *= invn; dz *= invn;
        float4 A4 = make_float4(ox, oy, oz, dx);
        float4 B4 = make_float4(dy, dz, 0.0f, 0.0f);
        *(float4*)(rayod + (size_t)ray * 8)     = A4;
        *(float4*)(rayod + (size_t)ray * 8 + 4) = B4;
    }
}

// ================= fused plane-gather + MFMA MLP (coarse & fine) =================
// Block = 96 points = EXACTLY 2 rays (ray-aligned: no division, no span logic).
// FINE prologue: waves 0,1 recompute cdf/z_mid for rays 2b, 2b+1 (shuffle scans).
// Phase A: 288 (point,plane) tasks over 256 threads: depth + taps -> LDS (byte-off + half2 w).
// Phase B: three exact rounds of {8 threads/point x 8 channels} packed-fp16 gather -> LDS rows.
// Phase C: 6 MFMA tiles of 16 points over 4 waves (waves 0,1 take 2 tiles).
template<bool FINE>
__global__ __launch_bounds__(256, 6) void fused_sample_mlp(
    const __half* __restrict__ planes,     // (6,256,256,64) interleaved fp16
    const float* __restrict__ rayod,       // per-ray {o,dnorm} packed (8 floats)
    const float* __restrict__ noise,       // coarse only
    const float* __restrict__ impu,        // fine only
    const float* __restrict__ depths_c,    // fine only (read, per-ray rows)
    const float* __restrict__ sigc,        // fine only (coarse sigma, scalar array)
    float* __restrict__ depths_out,        // write: depths_c (coarse) / depths_f (fine)
    const __half* __restrict__ w1f, const float* __restrict__ w2f,
    const float* __restrict__ b1f, const float* __restrict__ b2,
    float4* __restrict__ outRGBS,          // [point]
    float* __restrict__ sig_out)           // coarse only: scalar sigma copy
{
    __shared__ __half lds_x[BPTS][72];         // feature rows (fp16), stride 72 halves
    __shared__ int2  s_tap[BPTS][12];          // (byte offset, packed half2 weight)
    __shared__ float s_cdf[2][48];             // FINE: [0..45] cdf per local ray
    __shared__ float s_zm[2][48];              // FINE: [0..46] z_mid per local ray

    int tid = threadIdx.x;
    int rbase = blockIdx.x * 2;                // first ray of this block

    if constexpr (FINE) {
        int wv = tid >> 6, lane = tid & 63;
        if (wv < 2) {                          // one wave per ray, always exactly 2 rays
            int ray = rbase + wv;
            float d = 0.f, sg = 0.f;
            if (lane < NC_) {
                d  = depths_c[ray * NC_ + lane];
                sg = sigc[ray * NC_ + lane];
            }
            float dn = __shfl_down(d, 1, 64);
            float sn = __shfl_down(sg, 1, 64);
            bool iv = (lane < NC_ - 1);
            float zm = 0.5f * (d + dn);
            float alpha = 0.f, f = 1.0f;
            if (iv) {
                float dens = softplusf(0.5f * (sg + sn) - 1.0f);
                alpha = 1.0f - __expf(-dens * (dn - d));
                f = 1.0f - alpha + 1e-10f;
            }
            float x = f;
#pragma unroll
            for (int s = 1; s < 64; s <<= 1) {
                float t = __shfl_up(x, s, 64);
                if (lane >= s) x *= t;
            }
            float excl = __shfl_up(x, 1, 64);
            if (lane == 0) excl = 1.0f;
            float w = alpha * excl;
            float wprev = __shfl_up(w, 1, 64);
            float wmax;
            if (lane == 0) wmax = w;
            else if (lane == NC_ - 1) wmax = wprev;
            else wmax = fmaxf(wprev, w);
            float wmaxn = __shfl_down(wmax, 1, 64);
            float wb = 0.5f * (wmax + wmaxn) + 0.01f;
            float v = (lane >= 1 && lane <= 45) ? wb : 0.0f;
            float ssum = v;
#pragma unroll
            for (int mask = 1; mask <= 32; mask <<= 1) ssum += __shfl_xor(ssum, mask, 64);
            float pdf = v / ssum;
            float cum = pdf;
#pragma unroll
            for (int st = 1; st < 64; st <<= 1) {
                float t = __shfl_up(cum, st, 64);
                if (lane >= st) cum += t;
            }
            if (lane <= 45) s_cdf[wv][lane] = (lane == 0) ? 0.0f : cum;
            if (iv) s_zm[wv][lane] = zm;
        }
        __syncthreads();
    }

    // ---------------- phase A: 288 (point,plane) tasks over 256 threads ----------------
#pragma unroll 1
    for (int task = tid; task < 3 * BPTS; task += 256) {
        int pp = (task >= 2 * BPTS) ? 2 : ((task >= BPTS) ? 1 : 0);
        int p  = task - pp * BPTS;             // [0,96)
        int hi = (p >= NC_) ? 1 : 0;
        int s  = p - hi * NC_;                 // sample within ray
        int ray = rbase + hi;
        int point = ray * NC_ + s;             // == blockIdx.x*BPTS + p
        int bIdx = ray >> 12;

        float t;
        if constexpr (!FINE) {
            const float delta = (1.0f - 0.1f) / (NC_ - 1);
            t = 0.1f + delta * (float)s + noise[point] * delta;
        } else {
            float u = impu[point];
            const float* cdf = s_cdf[hi];
            const float* zmp = s_zm[hi];
            int lo = 0, hi2 = 46;
            while (lo < hi2) { int mid = (lo + hi2) >> 1; if (cdf[mid] > u) hi2 = mid; else lo = mid + 1; }
            int below = max(lo - 1, 0);
            int above = min(lo, 45);
            float c0 = cdf[below], c1 = cdf[above];
            float b0 = zmp[below], b1v = zmp[above];
            float den = c1 - c0; if (den < 1e-5f) den = 1.0f;
            t = b0 + (u - c0) / den * (b1v - b0);
        }
        if (pp == 0) depths_out[point] = t;

        const float4 A4 = *(const float4*)(rayod + (size_t)ray * 8);
        const float4 B4 = *(const float4*)(rayod + (size_t)ray * 8 + 4);
        float px = A4.x + t * A4.w;
        float py = A4.y + t * B4.x;
        float pz = A4.z + t * B4.y;

        // projections: p0:(x,y) p1:(x,z) p2:(z,x)
        float U = (pp == 2) ? pz : px;
        float V = (pp == 0) ? py : ((pp == 1) ? pz : px);
        const float inv3 = 1.0f / 3.0f;

        float gx = (U + 1.0f) * 128.0f - 0.5f;
        float gy = (V + 1.0f) * 128.0f - 0.5f;
        float fgx = floorf(gx), fgy = floorf(gy);
        int x0 = (int)fgx, y0 = (int)fgy;
        float fx = gx - fgx, fy = gy - fgy;
#pragma unroll
        for (int k = 0; k < 4; ++k) {
            int dxk = k & 1, dyk = k >> 1;
            int xi = x0 + dxk, yi = y0 + dyk;
            float w = (dxk ? fx : 1.0f - fx) * (dyk ? fy : 1.0f - fy);
            bool valid = (xi >= 0) && (xi < HPL) && (yi >= 0) && (yi < HPL);
            int xc = min(max(xi, 0), HPL - 1);
            int yc = min(max(yi, 0), HPL - 1);
            int p3 = bIdx * 3 + pp;
            __half2 hw2 = __half2half2(__float2half(valid ? w * inv3 : 0.0f));
            s_tap[p][pp * 4 + k] = make_int2((((p3 * HPL) + yc) * HPL + xc) * 128,  // BYTE offset
                                             *(const int*)&hw2);
        }
    }
    __syncthreads();

    // ---------------- phase B: three exact rounds of {8 threads/point, 8 channels} ----------------
    {
        const char* pbase = (const char*)planes + (tid & 7) * 16;
#pragma unroll 1
        for (int round = 0; round < 3; ++round) {
            int p = (tid >> 3) + round * 32;
            int2 tap[12];
#pragma unroll
            for (int kk = 0; kk < 12; ++kk) tap[kk] = s_tap[p][kk];
            __half2 acc2[4];
#pragma unroll
            for (int i = 0; i < 4; ++i) acc2[i] = __half2half2(__float2half(0.0f));
#pragma unroll
            for (int kk = 0; kk < 12; ++kk) {
                __half2 w2 = *(const __half2*)&tap[kk].y;
                float4 v = *(const float4*)(pbase + tap[kk].x);
                union { float4 f; __half2 h[4]; } u;
                u.f = v;
#pragma unroll
                for (int i = 0; i < 4; ++i) acc2[i] = __hfma2(u.h[i], w2, acc2[i]);
            }
            *(uint4*)&lds_x[p][(tid & 7) * 8] = *(const uint4*)&acc2[0];
        }
    }
    __syncthreads();

    // ---------------- phase C: 6 tiles of 16 points over 4 waves ----------------
    int lane = tid & 63, wave = tid >> 6;
    int g = lane >> 4, c = lane & 15;
#pragma unroll 1
    for (int tile = wave; tile < 6; tile += 4) {
        int mrow = tile * 16 + c;
        half8 a0 = *(const half8*)(&lds_x[mrow][g * 8]);
        half8 a1 = *(const half8*)(&lds_x[mrow][32 + g * 8]);

        float o[4][4];
#pragma unroll
        for (int r = 0; r < 4; ++r)
#pragma unroll
            for (int q = 0; q < 4; ++q) o[r][q] = 0.0f;

#pragma unroll
        for (int t = 0; t < 4; ++t) {
            half8 bf0 = *(const half8*)(w1f + ((size_t)((t * 2 + 0) * 64 + lane)) * 8);
            half8 bf1 = *(const half8*)(w1f + ((size_t)((t * 2 + 1) * 64 + lane)) * 8);
            f32x4 z = {0.f, 0.f, 0.f, 0.f};
            z = __builtin_amdgcn_mfma_f32_16x16x32_f16(a0, bf0, z, 0, 0, 0);
            z = __builtin_amdgcn_mfma_f32_16x16x32_f16(a1, bf1, z, 0, 0, 0);
            float  b1s = b1f[t * 64 + lane];
            float4 w2  = *(const float4*)(w2f + (size_t)(t * 64 + lane) * 4);
#pragma unroll
            for (int r = 0; r < 4; ++r) {
                float sp = softplusf(z[r] + b1s);
                o[r][0] = fmaf(sp, w2.x, o[r][0]);
                o[r][1] = fmaf(sp, w2.y, o[r][1]);
                o[r][2] = fmaf(sp, w2.z, o[r][2]);
                o[r][3] = fmaf(sp, w2.w, o[r][3]);
            }
        }
#pragma unroll
        for (int mask = 1; mask <= 8; mask <<= 1)
#pragma unroll
            for (int r = 0; r < 4; ++r)
#pragma unroll
                for (int q = 0; q < 4; ++q) o[r][q] += __shfl_xor(o[r][q], mask, 64);

        if (c == 0) {
#pragma unroll
            for (int r = 0; r < 4; ++r) {
                int pt = blockIdx.x * BPTS + tile * 16 + g * 4 + r;
                float sig = o[r][0] + b2[0];
                float rr = sigmoidf(o[r][1] + b2[1]) * 1.002f - 0.001f;
                float gg = sigmoidf(o[r][2] + b2[2]) * 1.002f - 0.001f;
                float bb = sigmoidf(o[r][3] + b2[3]) * 1.002f - 0.001f;
                outRGBS[pt] = make_float4(rr, gg, bb, sig);
                if constexpr (!FINE) sig_out[pt] = sig;
            }
        }
    }
}

// ---- merge + final march: ONE WAVE PER RAY, lane-parallel rank-merge + scan ----
#define FM_WAVES 4
__global__ __launch_bounds__(256) void final_march(
    const float* __restrict__ depths_c, const float4* __restrict__ rgbs_c,
    const float* __restrict__ depths_f, const float4* __restrict__ rgbs_f,
    const float* __restrict__ part_mn, const float* __restrict__ part_mx,
    float* __restrict__ out)
{
    __shared__ float s_dc[FM_WAVES][NC_];
    __shared__ float s_df[FM_WAVES][NI_];
    __shared__ float s_md[FM_WAVES][96];
    __shared__ float s_ms[FM_WAVES][96];
    __shared__ float s_mr[FM_WAVES][96];
    __shared__ float s_mg[FM_WAVES][96];
    __shared__ float s_mb[FM_WAVES][96];

    int wave = threadIdx.x >> 6, lane = threadIdx.x & 63;
    int ray = blockIdx.x * FM_WAVES + wave;
    float* dcp = s_dc[wave];
    float* dfp = s_df[wave];
    float* mdp = s_md[wave];
    float* msp = s_ms[wave];
    float* mrp = s_mr[wave];
    float* mgp = s_mg[wave];
    float* mbp = s_mb[wave];

    float dcv = 0.f, dfv = 0.f;
    float4 c4 = make_float4(0, 0, 0, 0), f4 = make_float4(0, 0, 0, 0);
    if (lane < NC_) {
        dcv = depths_c[ray * NC_ + lane];
        dfv = depths_f[ray * NI_ + lane];
        dcp[lane] = dcv;
        dfp[lane] = dfv;
        c4 = rgbs_c[ray * NC_ + lane];
        f4 = rgbs_f[ray * NI_ + lane];
    }
    __syncthreads();

    if (lane < NC_) {
        int cntC = 0, rankF = 0, cntCle = 0;
#pragma unroll
        for (int j = 0; j < NC_; ++j) {
            float dfj = dfp[j];
            float dcj = dcp[j];
            cntC   += (dfj < dcv) ? 1 : 0;
            rankF  += ((dfj < dfv) || (dfj == dfv && j < lane)) ? 1 : 0;
            cntCle += (dcj <= dfv) ? 1 : 0;
        }
        int posC = lane + cntC;          // stable: coarse before equal fine
        int posF = rankF + cntCle;
        mdp[posC] = dcv; msp[posC] = c4.w; mrp[posC] = c4.x; mgp[posC] = c4.y; mbp[posC] = c4.z;
        mdp[posF] = dfv; msp[posF] = f4.w; mrp[posF] = f4.x; mgp[posF] = f4.y; mbp[posF] = f4.z;
    }
    __syncthreads();

    int k0 = 2 * lane;
    int i0 = min(k0, 95), i1 = min(k0 + 1, 95), i2 = min(k0 + 2, 95);
    float d0 = mdp[i0], d1 = mdp[i1], d2 = mdp[i2];
    float sg0 = msp[i0], sg1 = msp[i1], sg2 = msp[i2];
    float r0 = mrp[i0], r1 = mrp[i1], r2 = mrp[i2];
    float g0 = mgp[i0], g1 = mgp[i1], g2 = mgp[i2];
    float bb0 = mbp[i0], bb1 = mbp[i1], bb2 = mbp[i2];

    bool v0 = (k0 < 95), v1 = (k0 + 1 < 95);
    float a0 = 0.f, a1 = 0.f, f0 = 1.f, f1 = 1.f;
    if (v0) {
        float dens = softplusf(0.5f * (sg0 + sg1) - 1.0f);
        a0 = 1.0f - __expf(-dens * (d1 - d0));
        f0 = 1.0f - a0 + 1e-10f;
    }
    if (v1) {
        float dens = softplusf(0.5f * (sg1 + sg2) - 1.0f);
        a1 = 1.0f - __expf(-dens * (d2 - d1));
        f1 = 1.0f - a1 + 1e-10f;
    }

    float pl = f0 * f1;
    float x = pl;
#pragma unroll
    for (int d = 1; d < 64; d <<= 1) {
        float t = __shfl_up(x, d, 64);
        if (lane >= d) x *= t;
    }
    float excl = __shfl_up(x, 1, 64);
    if (lane == 0) excl = 1.0f;
    float w0 = a0 * excl;
    float w1 = a1 * excl * f0;

    float accR = w0 * 0.5f * (r0 + r1) + w1 * 0.5f * (r1 + r2);
    float accG = w0 * 0.5f * (g0 + g1) + w1 * 0.5f * (g1 + g2);
    float accB = w0 * 0.5f * (bb0 + bb1) + w1 * 0.5f * (bb1 + bb2);
    float accD = w0 * 0.5f * (d0 + d1) + w1 * 0.5f * (d1 + d2);
    float accW = w0 + w1;
#pragma unroll
    for (int mask = 1; mask <= 32; mask <<= 1) {
        accR += __shfl_xor(accR, mask, 64);
        accG += __shfl_xor(accG, mask, 64);
        accB += __shfl_xor(accB, mask, 64);
        accD += __shfl_xor(accD, mask, 64);
        accW += __shfl_xor(accW, mask, 64);
    }

    // global clip bounds from 16 partials (no atomics anywhere)
    float pmn = (lane < 16) ? part_mn[lane] : INFINITY;
    float pmx = (lane < 16) ? part_mx[lane] : -INFINITY;
#pragma unroll
    for (int mask = 1; mask <= 32; mask <<= 1) {
        pmn = fminf(pmn, __shfl_xor(pmn, mask, 64));
        pmx = fmaxf(pmx, __shfl_xor(pmx, mask, 64));
    }

    if (lane == 0) {
        float q = accD / accW;
        if (!isfinite(q)) q = 0.0f;
        q = fminf(fmaxf(q, pmn), pmx);
        out[ray * 3 + 0] = accR * 2.0f - 1.0f;
        out[ray * 3 + 1] = accG * 2.0f - 1.0f;
        out[ray * 3 + 2] = accB * 2.0f - 1.0f;
        out[3 * NRAY + ray] = q;
        out[4 * NRAY + ray] = accW;
    }
}

extern "C" void kernel_launch(void* const* d_in, const int* in_sizes, int n_in,
                              void* d_out, int out_size, void* d_ws, size_t ws_size,
                              hipStream_t stream)
{
    const float* planes_tex = (const float*)d_in[0];
    const float* planes_shp = (const float*)d_in[1];
    const float* origins    = (const float*)d_in[2];
    const float* raydirs    = (const float*)d_in[3];
    const float* W1 = (const float*)d_in[4];
    const float* b1 = (const float*)d_in[5];
    const float* W2 = (const float*)d_in[6];
    const float* b2 = (const float*)d_in[7];
    const float* noise = (const float*)d_in[8];
    const float* impu  = (const float*)d_in[9];
    float* out = (float*)d_out;

    char* ws = (char*)d_ws;
    __half*         planes_cl = (__half*)ws;                          // 50,331,648 B
    __half*         w1f       = (__half*)(ws + 50331648);             // 8,192 B
    float*          w2f       = (float*)(ws + 50339840);              // 4,096 B
    float*          b1f       = (float*)(ws + 50343936);              // 1,024 B
    float*          part_mn   = (float*)(ws + 50344960);              // 64 B
    float*          part_mx   = (float*)(ws + 50345024);              // 64 B
    float*  depths_c = (float*)(ws + 50345216);                       // 1,572,864 B
    float*  depths_f = (float*)(ws + 51918080);                       // 1,572,864 B
    float4* rgbs_c   = (float4*)(ws + 53490944);                      // 6,291,456 B
    float4* rgbs_f   = (float4*)(ws + 59782400);                      // 6,291,456 B
    float*  rayod    = (float*)(ws + 66073856);                       // 262,144 B
    float*  sigc     = (float*)(ws + 66336000);                       // 1,572,864 B

    setup_kernel<<<dim3(TR_BLOCKS + 1 + 16 + 32), dim3(256), 0, stream>>>(
        planes_tex, planes_shp, planes_cl, W1, b1, W2, w1f, w2f, b1f, part_mn, part_mx,
        noise, origins, raydirs, rayod);

    fused_sample_mlp<false><<<dim3(NPTS / BPTS), dim3(256), 0, stream>>>(
        planes_cl, rayod, noise, nullptr, nullptr, nullptr,
        depths_c, w1f, w2f, b1f, b2, rgbs_c, sigc);

    fused_sample_mlp<true><<<dim3(NPTS / BPTS), dim3(256), 0, stream>>>(
        planes_cl, rayod, nullptr, impu, depths_c, sigc,
        depths_f, w1f, w2f, b1f, b2, rgbs_f, nullptr);

    final_march<<<dim3(NRAY / FM_WAVES), dim3(256), 0, stream>>>(
        depths_c, rgbs_c, depths_f, rgbs_f, part_mn, part_mx, out);
}

// Round 6
// 271.533 us; speedup vs baseline: 1.1666x; 1.1666x over previous
//
#include <hip/hip_runtime.h>
#include <hip/hip_fp16.h>
#include <math.h>

#define NRAY 8192
#define NC_  48
#define NI_  48
#define HPL  256
#define HID  64
#define NPTS (NRAY * NC_)        // 393216 points per pass
#define BPTS 64                  // points per block (proven optimum of this structure)

typedef __attribute__((ext_vector_type(8))) _Float16 half8;  // 8 fp16 (4 VGPRs)
typedef __attribute__((ext_vector_type(4))) float f32x4;

__device__ __forceinline__ float softplusf(float x) {
    return fmaxf(x, 0.0f) + __logf(1.0f + __expf(-fabsf(x)));
}
__device__ __forceinline__ float sigmoidf(float x) {
    return 1.0f / (1.0f + __expf(-x));
}

// ================= setup mega-kernel =================
// blocks [0, 3072): transpose (p in [0,12), y in [0,256)) -> fp16 channel-last interleaved.
// block 3072: weight fragment prep (fp16 W1 fragments).
// blocks 3073..3088: minmax partials from noise (no atomics).
// blocks 3089..3120: per-ray dir normalization -> rayod[ray*8] = {ox,oy,oz,dx,dy,dz,0,0}
#define TR_BLOCKS 3072
__global__ __launch_bounds__(256) void setup_kernel(
    const float* __restrict__ tex, const float* __restrict__ shp,
    __half* __restrict__ planes_cl,
    const float* __restrict__ W1, const float* __restrict__ b1, const float* __restrict__ W2,
    __half* __restrict__ w1f, float* __restrict__ w2f, float* __restrict__ b1f,
    float* __restrict__ part_mn, float* __restrict__ part_mx,
    const float* __restrict__ noise,
    const float* __restrict__ origins, const float* __restrict__ dirs,
    float* __restrict__ rayod)
{
    __shared__ __half t2[256][40];     // [x][c]; rows 80B -> 16B-aligned b128 reads, 2-way write conflict (free)
    __shared__ float smn[4], smx[4];
    int b = blockIdx.x;
    int tid = threadIdx.x;
    if (b < TR_BLOCKS) {
        int p = b >> 8;                // [0,12)
        int y = b & 255;
        const float* in = (p < 6) ? tex : shp;
        int pp    = (p < 6) ? p : p - 6;
        int choff = (p < 6) ? 0 : 32;
        const float* base = in + ((size_t)(pp * 32) * 256 + y) * 256;   // base[c*65536 + x]
        int lane6 = tid & 63;          // x-group within wave
        int cb    = (tid >> 6) * 8;    // c base: 0,8,16,24 per wave
        int x0    = lane6 * 4;
#pragma unroll
        for (int i = 0; i < 8; ++i) {
            float4 v = *(const float4*)(base + (size_t)(cb + i) * 65536 + x0);
            t2[x0 + 0][cb + i] = __float2half(v.x);
            t2[x0 + 1][cb + i] = __float2half(v.y);
            t2[x0 + 2][cb + i] = __float2half(v.z);
            t2[x0 + 3][cb + i] = __float2half(v.w);
        }
        __syncthreads();
        __half* outRow = planes_cl + ((size_t)(pp * 256 + y) * 256) * 64 + choff;
#pragma unroll
        for (int it = 0; it < 4; ++it) {
            int idx = it * 256 + tid;
            int x = idx >> 2, c8 = (idx & 3) * 8;
            *(uint4*)(outRow + (size_t)x * 64 + c8) = *(const uint4*)&t2[x][c8];
        }
    } else if (b == TR_BLOCKS) {
        int l = tid;
        if (l < 64) {
            int g = l >> 4, c = l & 15;
#pragma unroll
            for (int t = 0; t < 4; ++t) {
#pragma unroll
                for (int kb = 0; kb < 2; ++kb)
#pragma unroll
                    for (int j = 0; j < 8; ++j)
                        w1f[((t * 2 + kb) * 64 + l) * 8 + j] =
                            __float2half(W1[(kb * 32 + g * 8 + j) * HID + t * 16 + c]);
#pragma unroll
                for (int o = 0; o < 4; ++o) w2f[(t * 64 + l) * 4 + o] = W2[(t * 16 + c) * 4 + o];
                b1f[t * 64 + l] = b1[t * 16 + c];
            }
        }
    } else if (b < TR_BLOCKS + 17) {
        // minmax partials
        int bl = b - TR_BLOCKS - 1;            // [0,16)
        int gtid = bl * 256 + tid;             // [0,4096)
        float mn = INFINITY, mx = -INFINITY;
        for (int r = gtid; r < NRAY; r += 4096) {
            mn = fminf(mn, noise[r * NC_]);
            mx = fmaxf(mx, noise[r * NC_ + NC_ - 1]);
        }
#pragma unroll
        for (int mask = 1; mask <= 32; mask <<= 1) {
            mn = fminf(mn, __shfl_xor(mn, mask, 64));
            mx = fmaxf(mx, __shfl_xor(mx, mask, 64));
        }
        int wv = tid >> 6;
        if ((tid & 63) == 0) { smn[wv] = mn; smx[wv] = mx; }
        __syncthreads();
        if (tid == 0) {
#pragma unroll
            for (int i = 1; i < 4; ++i) { mn = fminf(mn, smn[i]); mx = fmaxf(mx, smx[i]); }
            const float delta = (1.0f - 0.1f) / (NC_ - 1);
            part_mn[bl] = 0.1f + mn * delta;                    // s = 0 term
            part_mx[bl] = 0.1f + delta * 47.0f + mx * delta;    // s = 47 term
        }
    } else {
        // per-ray normalized direction precompute
        int ray = (b - TR_BLOCKS - 17) * 256 + tid;             // [0,8192)
        float ox = origins[ray * 3 + 0], oy = origins[ray * 3 + 1], oz = origins[ray * 3 + 2];
        float dx = dirs[ray * 3 + 0], dy = dirs[ray * 3 + 1], dz = dirs[ray * 3 + 2];
        float invn = 1.0f / sqrtf(dx * dx + dy * dy + dz * dz);
        dx *= invn; dy *= invn; dz *= invn;
        float4 A4 = make_float4(ox, oy, oz, dx);
        float4 B4 = make_float4(dy, dz, 0.0f, 0.0f);
        *(float4*)(rayod + (size_t)ray * 8)     = A4;
        *(float4*)(rayod + (size_t)ray * 8 + 4) = B4;
    }
}

// ================= fused plane-gather + MFMA MLP (coarse & fine) =================
// Block = 64 points (BPTS). A 64-pt block spans at most 2 rays (offsets mod 48 cycle {0,16,32};
// 32+63=95 < 96), so the 2-ray FINE prologue applies.
// FINE prologue: waves 0-1 recompute the cdf/z_mid of the <=2 rays this block spans.
// Phase A: 192 threads (1 per point-plane): depth + taps -> LDS (BYTE offset + packed half2 w).
// Phase B: two rounds of {8 threads/point x 8 channels} packed-fp16 gather -> LDS rows (fp16).
// Phase C: ALL 4 waves run the f16 MFMA MLP, 16 points each.
template<bool FINE>
__global__ __launch_bounds__(256, 8) void fused_sample_mlp(
    const __half* __restrict__ planes,     // (6,256,256,64) interleaved fp16
    const float* __restrict__ rayod,       // per-ray {o,dnorm} packed (8 floats)
    const float* __restrict__ noise,       // coarse only
    const float* __restrict__ impu,        // fine only
    const float* __restrict__ depths_c,    // fine only (read, per-ray rows)
    const float4* __restrict__ rgbs_c_in,  // fine only (read sigma)
    float* __restrict__ depths_out,        // write: depths_c (coarse) / depths_f (fine)
    const __half* __restrict__ w1f, const float* __restrict__ w2f,
    const float* __restrict__ b1f, const float* __restrict__ b2,
    float4* __restrict__ outRGBS)          // [point]
{
    __shared__ __half lds_x[BPTS][72];         // feature rows (fp16), stride 72 halves
    __shared__ int s_tap[BPTS][12][2];         // (byte offset, packed half2 weight)
    __shared__ float s_cdf[2][48];             // FINE: [0..45] cdf per local ray
    __shared__ float s_zm[2][48];              // FINE: [0..46] z_mid per local ray

    int tid = threadIdx.x;
    int r0 = (blockIdx.x * BPTS) / NC_;

    if constexpr (FINE) {
        int wv = tid >> 6, lane = tid & 63;
        int r1 = (blockIdx.x * BPTS + BPTS - 1) / NC_;
        if (wv <= r1 - r0) {                   // wave 0 always; wave 1 iff block spans 2 rays
            int ray = r0 + wv;
            float d = 0.f, sg = 0.f;
            if (lane < NC_) {
                d  = depths_c[ray * NC_ + lane];
                sg = rgbs_c_in[ray * NC_ + lane].w;
            }
            float dn = __shfl_down(d, 1, 64);
            float sn = __shfl_down(sg, 1, 64);
            bool iv = (lane < NC_ - 1);
            float zm = 0.5f * (d + dn);
            float alpha = 0.f, f = 1.0f;
            if (iv) {
                float dens = softplusf(0.5f * (sg + sn) - 1.0f);
                alpha = 1.0f - __expf(-dens * (dn - d));
                f = 1.0f - alpha + 1e-10f;
            }
            float x = f;
#pragma unroll
            for (int s = 1; s < 64; s <<= 1) {
                float t = __shfl_up(x, s, 64);
                if (lane >= s) x *= t;
            }
            float excl = __shfl_up(x, 1, 64);
            if (lane == 0) excl = 1.0f;
            float w = alpha * excl;
            float wprev = __shfl_up(w, 1, 64);
            float wmax;
            if (lane == 0) wmax = w;
            else if (lane == NC_ - 1) wmax = wprev;
            else wmax = fmaxf(wprev, w);
            float wmaxn = __shfl_down(wmax, 1, 64);
            float wb = 0.5f * (wmax + wmaxn) + 0.01f;
            float v = (lane >= 1 && lane <= 45) ? wb : 0.0f;
            float ssum = v;
#pragma unroll
            for (int mask = 1; mask <= 32; mask <<= 1) ssum += __shfl_xor(ssum, mask, 64);
            float pdf = v / ssum;
            float cum = pdf;
#pragma unroll
            for (int st = 1; st < 64; st <<= 1) {
                float t = __shfl_up(cum, st, 64);
                if (lane >= st) cum += t;
            }
            if (lane <= 45) s_cdf[wv][lane] = (lane == 0) ? 0.0f : cum;
            if (iv) s_zm[wv][lane] = zm;
        }
        __syncthreads();
    }

    // ---------------- phase A: 1 thread per (point, plane), 192 active ----------------
    if (tid < 192) {
        int p  = tid & 63;
        int pp = tid >> 6;                 // plane 0..2
        int point = blockIdx.x * BPTS + p;
        int ray = point / NC_;
        int bIdx = ray >> 12;

        float t;
        if constexpr (!FINE) {
            int s = point - ray * NC_;
            const float delta = (1.0f - 0.1f) / (NC_ - 1);
            t = 0.1f + delta * (float)s + noise[point] * delta;
        } else {
            int ridx = ray - r0;
            float u = impu[point];
            const float* cdf = s_cdf[ridx];
            const float* zmp = s_zm[ridx];
            int lo = 0, hi = 46;
            while (lo < hi) { int mid = (lo + hi) >> 1; if (cdf[mid] > u) hi = mid; else lo = mid + 1; }
            int below = max(lo - 1, 0);
            int above = min(lo, 45);
            float c0 = cdf[below], c1 = cdf[above];
            float b0 = zmp[below], b1v = zmp[above];
            float den = c1 - c0; if (den < 1e-5f) den = 1.0f;
            t = b0 + (u - c0) / den * (b1v - b0);
        }
        if (pp == 0) depths_out[point] = t;

        const float4 A4 = *(const float4*)(rayod + (size_t)ray * 8);
        const float4 B4 = *(const float4*)(rayod + (size_t)ray * 8 + 4);
        float px = A4.x + t * A4.w;
        float py = A4.y + t * B4.x;
        float pz = A4.z + t * B4.y;

        // projections: p0:(x,y) p1:(x,z) p2:(z,x)
        float U = (pp == 2) ? pz : px;
        float V = (pp == 0) ? py : ((pp == 1) ? pz : px);
        const float inv3 = 1.0f / 3.0f;

        float gx = (U + 1.0f) * 128.0f - 0.5f;
        float gy = (V + 1.0f) * 128.0f - 0.5f;
        float fgx = floorf(gx), fgy = floorf(gy);
        int x0 = (int)fgx, y0 = (int)fgy;
        float fx = gx - fgx, fy = gy - fgy;
#pragma unroll
        for (int k = 0; k < 4; ++k) {
            int dxk = k & 1, dyk = k >> 1;
            int xi = x0 + dxk, yi = y0 + dyk;
            float w = (dxk ? fx : 1.0f - fx) * (dyk ? fy : 1.0f - fy);
            bool valid = (xi >= 0) && (xi < HPL) && (yi >= 0) && (yi < HPL);
            int xc = min(max(xi, 0), HPL - 1);
            int yc = min(max(yi, 0), HPL - 1);
            int p3 = bIdx * 3 + pp;
            __half2 hw2 = __half2half2(__float2half(valid ? w * inv3 : 0.0f));
            s_tap[p][pp * 4 + k][0] = (((p3 * HPL) + yc) * HPL + xc) * 128;   // BYTE offset
            s_tap[p][pp * 4 + k][1] = *(const int*)&hw2;
        }
    }
    __syncthreads();

    // ---------------- phase B: two rounds of {8 threads/point, 8 channels} ----------------
    {
        const char* pbase = (const char*)planes + (tid & 7) * 16;
#pragma unroll 1
        for (int round = 0; round < 2; ++round) {
            int p = (tid >> 3) + round * 32;
            int off[12];
            int wb[12];
#pragma unroll
            for (int kk = 0; kk < 12; ++kk) {
                off[kk] = s_tap[p][kk][0];
                wb[kk]  = s_tap[p][kk][1];
            }
            __half2 acc2[4];
#pragma unroll
            for (int i = 0; i < 4; ++i) acc2[i] = __half2half2(__float2half(0.0f));
#pragma unroll
            for (int kk = 0; kk < 12; ++kk) {
                __half2 w2 = *(const __half2*)&wb[kk];
                float4 v = *(const float4*)(pbase + off[kk]);
                union { float4 f; __half2 h[4]; } u;
                u.f = v;
#pragma unroll
                for (int i = 0; i < 4; ++i) acc2[i] = __hfma2(u.h[i], w2, acc2[i]);
            }
            *(uint4*)&lds_x[p][(tid & 7) * 8] = *(const uint4*)&acc2[0];
        }
    }
    __syncthreads();

    // ---------------- phase C: ALL 4 waves -> f16 MFMA MLP, 16 points each ----------------
    int lane = tid & 63, wave = tid >> 6;
    {
        int g = lane >> 4, c = lane & 15;
        int mrow = wave * 16 + c;
        half8 a0 = *(const half8*)(&lds_x[mrow][g * 8]);
        half8 a1 = *(const half8*)(&lds_x[mrow][32 + g * 8]);

        float o[4][4];
#pragma unroll
        for (int r = 0; r < 4; ++r)
#pragma unroll
            for (int q = 0; q < 4; ++q) o[r][q] = 0.0f;

#pragma unroll
        for (int t = 0; t < 4; ++t) {
            half8 bf0 = *(const half8*)(w1f + ((size_t)((t * 2 + 0) * 64 + lane)) * 8);
            half8 bf1 = *(const half8*)(w1f + ((size_t)((t * 2 + 1) * 64 + lane)) * 8);
            f32x4 z = {0.f, 0.f, 0.f, 0.f};
            z = __builtin_amdgcn_mfma_f32_16x16x32_f16(a0, bf0, z, 0, 0, 0);
            z = __builtin_amdgcn_mfma_f32_16x16x32_f16(a1, bf1, z, 0, 0, 0);
            float  b1s = b1f[t * 64 + lane];
            float4 w2  = *(const float4*)(w2f + (size_t)(t * 64 + lane) * 4);
#pragma unroll
            for (int r = 0; r < 4; ++r) {
                float sp = softplusf(z[r] + b1s);
                o[r][0] = fmaf(sp, w2.x, o[r][0]);
                o[r][1] = fmaf(sp, w2.y, o[r][1]);
                o[r][2] = fmaf(sp, w2.z, o[r][2]);
                o[r][3] = fmaf(sp, w2.w, o[r][3]);
            }
        }
#pragma unroll
        for (int mask = 1; mask <= 8; mask <<= 1)
#pragma unroll
            for (int r = 0; r < 4; ++r)
#pragma unroll
                for (int q = 0; q < 4; ++q) o[r][q] += __shfl_xor(o[r][q], mask, 64);

        if (c == 0) {
#pragma unroll
            for (int r = 0; r < 4; ++r) {
                int pt = blockIdx.x * BPTS + wave * 16 + g * 4 + r;
                float sig = o[r][0] + b2[0];
                float rr = sigmoidf(o[r][1] + b2[1]) * 1.002f - 0.001f;
                float gg = sigmoidf(o[r][2] + b2[2]) * 1.002f - 0.001f;
                float bb = sigmoidf(o[r][3] + b2[3]) * 1.002f - 0.001f;
                outRGBS[pt] = make_float4(rr, gg, bb, sig);
            }
        }
    }
}

// ---- merge + final march: ONE WAVE PER RAY, lane-parallel rank-merge + scan ----
#define FM_WAVES 4
__global__ __launch_bounds__(256) void final_march(
    const float* __restrict__ depths_c, const float4* __restrict__ rgbs_c,
    const float* __restrict__ depths_f, const float4* __restrict__ rgbs_f,
    const float* __restrict__ part_mn, const float* __restrict__ part_mx,
    float* __restrict__ out)
{
    __shared__ float s_dc[FM_WAVES][NC_];
    __shared__ float s_df[FM_WAVES][NI_];
    __shared__ float s_md[FM_WAVES][96];
    __shared__ float s_ms[FM_WAVES][96];
    __shared__ float s_mr[FM_WAVES][96];
    __shared__ float s_mg[FM_WAVES][96];
    __shared__ float s_mb[FM_WAVES][96];

    int wave = threadIdx.x >> 6, lane = threadIdx.x & 63;
    int ray = blockIdx.x * FM_WAVES + wave;
    float* dcp = s_dc[wave];
    float* dfp = s_df[wave];
    float* mdp = s_md[wave];
    float* msp = s_ms[wave];
    float* mrp = s_mr[wave];
    float* mgp = s_mg[wave];
    float* mbp = s_mb[wave];

    float dcv = 0.f, dfv = 0.f;
    float4 c4 = make_float4(0, 0, 0, 0), f4 = make_float4(0, 0, 0, 0);
    if (lane < NC_) {
        dcv = depths_c[ray * NC_ + lane];
        dfv = depths_f[ray * NI_ + lane];
        dcp[lane] = dcv;
        dfp[lane] = dfv;
        c4 = rgbs_c[ray * NC_ + lane];
        f4 = rgbs_f[ray * NI_ + lane];
    }
    __syncthreads();

    if (lane < NC_) {
        int cntC = 0, rankF = 0, cntCle = 0;
#pragma unroll
        for (int j = 0; j < NC_; ++j) {
            float dfj = dfp[j];
            float dcj = dcp[j];
            cntC   += (dfj < dcv) ? 1 : 0;
            rankF  += ((dfj < dfv) || (dfj == dfv && j < lane)) ? 1 : 0;
            cntCle += (dcj <= dfv) ? 1 : 0;
        }
        int posC = lane + cntC;          // stable: coarse before equal fine
        int posF = rankF + cntCle;
        mdp[posC] = dcv; msp[posC] = c4.w; mrp[posC] = c4.x; mgp[posC] = c4.y; mbp[posC] = c4.z;
        mdp[posF] = dfv; msp[posF] = f4.w; mrp[posF] = f4.x; mgp[posF] = f4.y; mbp[posF] = f4.z;
    }
    __syncthreads();

    int k0 = 2 * lane;
    int i0 = min(k0, 95), i1 = min(k0 + 1, 95), i2 = min(k0 + 2, 95);
    float d0 = mdp[i0], d1 = mdp[i1], d2 = mdp[i2];
    float sg0 = msp[i0], sg1 = msp[i1], sg2 = msp[i2];
    float r0 = mrp[i0], r1 = mrp[i1], r2 = mrp[i2];
    float g0 = mgp[i0], g1 = mgp[i1], g2 = mgp[i2];
    float bb0 = mbp[i0], bb1 = mbp[i1], bb2 = mbp[i2];

    bool v0 = (k0 < 95), v1 = (k0 + 1 < 95);
    float a0 = 0.f, a1 = 0.f, f0 = 1.f, f1 = 1.f;
    if (v0) {
        float dens = softplusf(0.5f * (sg0 + sg1) - 1.0f);
        a0 = 1.0f - __expf(-dens * (d1 - d0));
        f0 = 1.0f - a0 + 1e-10f;
    }
    if (v1) {
        float dens = softplusf(0.5f * (sg1 + sg2) - 1.0f);
        a1 = 1.0f - __expf(-dens * (d2 - d1));
        f1 = 1.0f - a1 + 1e-10f;
    }

    float pl = f0 * f1;
    float x = pl;
#pragma unroll
    for (int d = 1; d < 64; d <<= 1) {
        float t = __shfl_up(x, d, 64);
        if (lane >= d) x *= t;
    }
    float excl = __shfl_up(x, 1, 64);
    if (lane == 0) excl = 1.0f;
    float w0 = a0 * excl;
    float w1 = a1 * excl * f0;

    float accR = w0 * 0.5f * (r0 + r1) + w1 * 0.5f * (r1 + r2);
    float accG = w0 * 0.5f * (g0 + g1) + w1 * 0.5f * (g1 + g2);
    float accB = w0 * 0.5f * (bb0 + bb1) + w1 * 0.5f * (bb1 + bb2);
    float accD = w0 * 0.5f * (d0 + d1) + w1 * 0.5f * (d1 + d2);
    float accW = w0 + w1;
#pragma unroll
    for (int mask = 1; mask <= 32; mask <<= 1) {
        accR += __shfl_xor(accR, mask, 64);
        accG += __shfl_xor(accG, mask, 64);
        accB += __shfl_xor(accB, mask, 64);
        accD += __shfl_xor(accD, mask, 64);
        accW += __shfl_xor(accW, mask, 64);
    }

    // global clip bounds from 16 partials (no atomics anywhere)
    float pmn = (lane < 16) ? part_mn[lane] : INFINITY;
    float pmx = (lane < 16) ? part_mx[lane] : -INFINITY;
#pragma unroll
    for (int mask = 1; mask <= 32; mask <<= 1) {
        pmn = fminf(pmn, __shfl_xor(pmn, mask, 64));
        pmx = fmaxf(pmx, __shfl_xor(pmx, mask, 64));
    }

    if (lane == 0) {
        float q = accD / accW;
        if (!isfinite(q)) q = 0.0f;
        q = fminf(fmaxf(q, pmn), pmx);
        out[ray * 3 + 0] = accR * 2.0f - 1.0f;
        out[ray * 3 + 1] = accG * 2.0f - 1.0f;
        out[ray * 3 + 2] = accB * 2.0f - 1.0f;
        out[3 * NRAY + ray] = q;
        out[4 * NRAY + ray] = accW;
    }
}

extern "C" void kernel_launch(void* const* d_in, const int* in_sizes, int n_in,
                              void* d_out, int out_size, void* d_ws, size_t ws_size,
                              hipStream_t stream)
{
    const float* planes_tex = (const float*)d_in[0];
    const float* planes_shp = (const float*)d_in[1];
    const float* origins    = (const float*)d_in[2];
    const float* raydirs    = (const float*)d_in[3];
    const float* W1 = (const float*)d_in[4];
    const float* b1 = (const float*)d_in[5];
    const float* W2 = (const float*)d_in[6];
    const float* b2 = (const float*)d_in[7];
    const float* noise = (const float*)d_in[8];
    const float* impu  = (const float*)d_in[9];
    float* out = (float*)d_out;

    char* ws = (char*)d_ws;
    __half*         planes_cl = (__half*)ws;                          // 50,331,648 B
    __half*         w1f       = (__half*)(ws + 50331648);             // 8,192 B
    float*          w2f       = (float*)(ws + 50339840);              // 4,096 B
    float*          b1f       = (float*)(ws + 50343936);              // 1,024 B
    float*          part_mn   = (float*)(ws + 50344960);              // 64 B
    float*          part_mx   = (float*)(ws + 50345024);              // 64 B
    float*  depths_c = (float*)(ws + 50345216);                       // 1,572,864 B
    float*  depths_f = (float*)(ws + 51918080);                       // 1,572,864 B
    float4* rgbs_c   = (float4*)(ws + 53490944);                      // 6,291,456 B
    float4* rgbs_f   = (float4*)(ws + 59782400);                      // 6,291,456 B
    float*  rayod    = (float*)(ws + 66073856);                       // 262,144 B

    setup_kernel<<<dim3(TR_BLOCKS + 1 + 16 + 32), dim3(256), 0, stream>>>(
        planes_tex, planes_shp, planes_cl, W1, b1, W2, w1f, w2f, b1f, part_mn, part_mx,
        noise, origins, raydirs, rayod);

    fused_sample_mlp<false><<<dim3(NPTS / BPTS), dim3(256), 0, stream>>>(
        planes_cl, rayod, noise, nullptr, nullptr, nullptr,
        depths_c, w1f, w2f, b1f, b2, rgbs_c);

    fused_sample_mlp<true><<<dim3(NPTS / BPTS), dim3(256), 0, stream>>>(
        planes_cl, rayod, nullptr, impu, depths_c, rgbs_c,
        depths_f, w1f, w2f, b1f, b2, rgbs_f);

    final_march<<<dim3(NRAY / FM_WAVES), dim3(256), 0, stream>>>(
        depths_c, rgbs_c, depths_f, rgbs_f, part_mn, part_mx, out);
}

// Round 7
// 269.266 us; speedup vs baseline: 1.1764x; 1.0084x over previous
//
#include <hip/hip_runtime.h>
#include <hip/hip_fp16.h>
#include <math.h>

#define NRAY 8192
#define NC_  48
#define NI_  48
#define HPL  256
#define HID  64
#define NPTS (NRAY * NC_)        // 393216 points per pass
#define BPTS 64                  // points per block (proven optimum of this structure)

typedef __attribute__((ext_vector_type(8))) _Float16 half8;  // 8 fp16 (4 VGPRs)
typedef __attribute__((ext_vector_type(4))) float f32x4;

__device__ __forceinline__ float softplusf(float x) {
    return fmaxf(x, 0.0f) + __logf(1.0f + __expf(-fabsf(x)));
}
__device__ __forceinline__ float sigmoidf(float x) {
    return 1.0f / (1.0f + __expf(-x));
}

// ================= setup mega-kernel =================
// blocks [0, 3072): transpose (p in [0,12), y in [0,256)) -> fp16 channel-last interleaved.
// block 3072: weight fragment prep (fp16 W1 fragments).
// blocks 3073..3088: minmax partials from noise (no atomics).
// blocks 3089..3120: per-ray dir normalization -> rayod[ray*8] = {ox,oy,oz,dx,dy,dz,0,0}
#define TR_BLOCKS 3072
__global__ __launch_bounds__(256) void setup_kernel(
    const float* __restrict__ tex, const float* __restrict__ shp,
    __half* __restrict__ planes_cl,
    const float* __restrict__ W1, const float* __restrict__ b1, const float* __restrict__ W2,
    __half* __restrict__ w1f, float* __restrict__ w2f, float* __restrict__ b1f,
    float* __restrict__ part_mn, float* __restrict__ part_mx,
    const float* __restrict__ noise,
    const float* __restrict__ origins, const float* __restrict__ dirs,
    float* __restrict__ rayod)
{
    __shared__ __half t2[256][40];     // [x][c]; rows 80B -> 16B-aligned b128 reads, 2-way write conflict (free)
    __shared__ float smn[4], smx[4];
    int b = blockIdx.x;
    int tid = threadIdx.x;
    if (b < TR_BLOCKS) {
        int p = b >> 8;                // [0,12)
        int y = b & 255;
        const float* in = (p < 6) ? tex : shp;
        int pp    = (p < 6) ? p : p - 6;
        int choff = (p < 6) ? 0 : 32;
        const float* base = in + ((size_t)(pp * 32) * 256 + y) * 256;   // base[c*65536 + x]
        int lane6 = tid & 63;          // x-group within wave
        int cb    = (tid >> 6) * 8;    // c base: 0,8,16,24 per wave
        int x0    = lane6 * 4;
#pragma unroll
        for (int i = 0; i < 8; ++i) {
            float4 v = *(const float4*)(base + (size_t)(cb + i) * 65536 + x0);
            t2[x0 + 0][cb + i] = __float2half(v.x);
            t2[x0 + 1][cb + i] = __float2half(v.y);
            t2[x0 + 2][cb + i] = __float2half(v.z);
            t2[x0 + 3][cb + i] = __float2half(v.w);
        }
        __syncthreads();
        __half* outRow = planes_cl + ((size_t)(pp * 256 + y) * 256) * 64 + choff;
#pragma unroll
        for (int it = 0; it < 4; ++it) {
            int idx = it * 256 + tid;
            int x = idx >> 2, c8 = (idx & 3) * 8;
            *(uint4*)(outRow + (size_t)x * 64 + c8) = *(const uint4*)&t2[x][c8];
        }
    } else if (b == TR_BLOCKS) {
        int l = tid;
        if (l < 64) {
            int g = l >> 4, c = l & 15;
#pragma unroll
            for (int t = 0; t < 4; ++t) {
#pragma unroll
                for (int kb = 0; kb < 2; ++kb)
#pragma unroll
                    for (int j = 0; j < 8; ++j)
                        w1f[((t * 2 + kb) * 64 + l) * 8 + j] =
                            __float2half(W1[(kb * 32 + g * 8 + j) * HID + t * 16 + c]);
#pragma unroll
                for (int o = 0; o < 4; ++o) w2f[(t * 64 + l) * 4 + o] = W2[(t * 16 + c) * 4 + o];
                b1f[t * 64 + l] = b1[t * 16 + c];
            }
        }
    } else if (b < TR_BLOCKS + 17) {
        // minmax partials
        int bl = b - TR_BLOCKS - 1;            // [0,16)
        int gtid = bl * 256 + tid;             // [0,4096)
        float mn = INFINITY, mx = -INFINITY;
        for (int r = gtid; r < NRAY; r += 4096) {
            mn = fminf(mn, noise[r * NC_]);
            mx = fmaxf(mx, noise[r * NC_ + NC_ - 1]);
        }
#pragma unroll
        for (int mask = 1; mask <= 32; mask <<= 1) {
            mn = fminf(mn, __shfl_xor(mn, mask, 64));
            mx = fmaxf(mx, __shfl_xor(mx, mask, 64));
        }
        int wv = tid >> 6;
        if ((tid & 63) == 0) { smn[wv] = mn; smx[wv] = mx; }
        __syncthreads();
        if (tid == 0) {
#pragma unroll
            for (int i = 1; i < 4; ++i) { mn = fminf(mn, smn[i]); mx = fmaxf(mx, smx[i]); }
            const float delta = (1.0f - 0.1f) / (NC_ - 1);
            part_mn[bl] = 0.1f + mn * delta;                    // s = 0 term
            part_mx[bl] = 0.1f + delta * 47.0f + mx * delta;    // s = 47 term
        }
    } else {
        // per-ray normalized direction precompute
        int ray = (b - TR_BLOCKS - 17) * 256 + tid;             // [0,8192)
        float ox = origins[ray * 3 + 0], oy = origins[ray * 3 + 1], oz = origins[ray * 3 + 2];
        float dx = dirs[ray * 3 + 0], dy = dirs[ray * 3 + 1], dz = dirs[ray * 3 + 2];
        float invn = 1.0f / sqrtf(dx * dx + dy * dy + dz * dz);
        dx *= invn; dy *= invn; dz *= invn;
        float4 A4 = make_float4(ox, oy, oz, dx);
        float4 B4 = make_float4(dy, dz, 0.0f, 0.0f);
        *(float4*)(rayod + (size_t)ray * 8)     = A4;
        *(float4*)(rayod + (size_t)ray * 8 + 4) = B4;
    }
}

// ================= fused plane-gather + MFMA MLP (coarse & fine) =================
// Block = 64 points. WAVE-PRIVATE pipeline: each wave owns 16 points end-to-end:
//   Phase A (lanes 0-47): taps for points wave*16..+16, planes 0..2 -> s_tap rows [wave*16,+16)
//   Phase B: 2 rounds, p = wave*16 + round*8 + (lane>>3), 8 ch each -> lds_x rows [wave*16,+16)
//   Phase C: MFMA MLP on rows wave*16+c  (same rows)
// All LDS producer->consumer edges are wave-internal => NO __syncthreads in coarse.
// FINE: cdf prologue is cross-wave (waves 0,1 compute the <=2 rays) => ONE barrier after it.
template<bool FINE>
__global__ __launch_bounds__(256, 8) void fused_sample_mlp(
    const __half* __restrict__ planes,     // (6,256,256,64) interleaved fp16
    const float* __restrict__ rayod,       // per-ray {o,dnorm} packed (8 floats)
    const float* __restrict__ noise,       // coarse only
    const float* __restrict__ impu,        // fine only
    const float* __restrict__ depths_c,    // fine only (read, per-ray rows)
    const float4* __restrict__ rgbs_c_in,  // fine only (read sigma)
    float* __restrict__ depths_out,        // write: depths_c (coarse) / depths_f (fine)
    const __half* __restrict__ w1f, const float* __restrict__ w2f,
    const float* __restrict__ b1f, const float* __restrict__ b2,
    float4* __restrict__ outRGBS)          // [point]
{
    __shared__ __half lds_x[BPTS][72];         // feature rows (fp16), stride 72 halves
    __shared__ int s_tap[BPTS][12][2];         // (byte offset, packed half2 weight)
    __shared__ float s_cdf[2][48];             // FINE: [0..45] cdf per local ray
    __shared__ float s_zm[2][48];              // FINE: [0..46] z_mid per local ray

    int tid = threadIdx.x;
    int wave = tid >> 6, lane = tid & 63;
    int r0 = (blockIdx.x * BPTS) / NC_;

    if constexpr (FINE) {
        int r1 = (blockIdx.x * BPTS + BPTS - 1) / NC_;
        if (wave <= r1 - r0) {                 // wave 0 always; wave 1 iff block spans 2 rays
            int ray = r0 + wave;
            float d = 0.f, sg = 0.f;
            if (lane < NC_) {
                d  = depths_c[ray * NC_ + lane];
                sg = rgbs_c_in[ray * NC_ + lane].w;
            }
            float dn = __shfl_down(d, 1, 64);
            float sn = __shfl_down(sg, 1, 64);
            bool iv = (lane < NC_ - 1);
            float zm = 0.5f * (d + dn);
            float alpha = 0.f, f = 1.0f;
            if (iv) {
                float dens = softplusf(0.5f * (sg + sn) - 1.0f);
                alpha = 1.0f - __expf(-dens * (dn - d));
                f = 1.0f - alpha + 1e-10f;
            }
            float x = f;
#pragma unroll
            for (int s = 1; s < 64; s <<= 1) {
                float t = __shfl_up(x, s, 64);
                if (lane >= s) x *= t;
            }
            float excl = __shfl_up(x, 1, 64);
            if (lane == 0) excl = 1.0f;
            float w = alpha * excl;
            float wprev = __shfl_up(w, 1, 64);
            float wmax;
            if (lane == 0) wmax = w;
            else if (lane == NC_ - 1) wmax = wprev;
            else wmax = fmaxf(wprev, w);
            float wmaxn = __shfl_down(wmax, 1, 64);
            float wb = 0.5f * (wmax + wmaxn) + 0.01f;
            float v = (lane >= 1 && lane <= 45) ? wb : 0.0f;
            float ssum = v;
#pragma unroll
            for (int mask = 1; mask <= 32; mask <<= 1) ssum += __shfl_xor(ssum, mask, 64);
            float pdf = v / ssum;
            float cum = pdf;
#pragma unroll
            for (int st = 1; st < 64; st <<= 1) {
                float t = __shfl_up(cum, st, 64);
                if (lane >= st) cum += t;
            }
            if (lane <= 45) s_cdf[wave][lane] = (lane == 0) ? 0.0f : cum;
            if (iv) s_zm[wave][lane] = zm;
        }
        __syncthreads();                       // the ONLY barrier (cdf is cross-wave)
    }

    // ---------------- phase A: wave-private taps (lanes 0-47: 16 points x 3 planes) --------
    if (lane < 48) {
        int p  = wave * 16 + (lane & 15);      // this wave's point rows
        int pp = lane >> 4;                    // plane 0..2
        int point = blockIdx.x * BPTS + p;
        int ray = point / NC_;
        int bIdx = ray >> 12;

        float t;
        if constexpr (!FINE) {
            int s = point - ray * NC_;
            const float delta = (1.0f - 0.1f) / (NC_ - 1);
            t = 0.1f + delta * (float)s + noise[point] * delta;
        } else {
            int ridx = ray - r0;
            float u = impu[point];
            const float* cdf = s_cdf[ridx];
            const float* zmp = s_zm[ridx];
            int lo = 0, hi = 46;
            while (lo < hi) { int mid = (lo + hi) >> 1; if (cdf[mid] > u) hi = mid; else lo = mid + 1; }
            int below = max(lo - 1, 0);
            int above = min(lo, 45);
            float c0 = cdf[below], c1 = cdf[above];
            float b0 = zmp[below], b1v = zmp[above];
            float den = c1 - c0; if (den < 1e-5f) den = 1.0f;
            t = b0 + (u - c0) / den * (b1v - b0);
        }
        if (pp == 0) depths_out[point] = t;

        const float4 A4 = *(const float4*)(rayod + (size_t)ray * 8);
        const float4 B4 = *(const float4*)(rayod + (size_t)ray * 8 + 4);
        float px = A4.x + t * A4.w;
        float py = A4.y + t * B4.x;
        float pz = A4.z + t * B4.y;

        // projections: p0:(x,y) p1:(x,z) p2:(z,x)
        float U = (pp == 2) ? pz : px;
        float V = (pp == 0) ? py : ((pp == 1) ? pz : px);
        const float inv3 = 1.0f / 3.0f;

        float gx = (U + 1.0f) * 128.0f - 0.5f;
        float gy = (V + 1.0f) * 128.0f - 0.5f;
        float fgx = floorf(gx), fgy = floorf(gy);
        int x0 = (int)fgx, y0 = (int)fgy;
        float fx = gx - fgx, fy = gy - fgy;
#pragma unroll
        for (int k = 0; k < 4; ++k) {
            int dxk = k & 1, dyk = k >> 1;
            int xi = x0 + dxk, yi = y0 + dyk;
            float w = (dxk ? fx : 1.0f - fx) * (dyk ? fy : 1.0f - fy);
            bool valid = (xi >= 0) && (xi < HPL) && (yi >= 0) && (yi < HPL);
            int xc = min(max(xi, 0), HPL - 1);
            int yc = min(max(yi, 0), HPL - 1);
            int p3 = bIdx * 3 + pp;
            __half2 hw2 = __half2half2(__float2half(valid ? w * inv3 : 0.0f));
            s_tap[p][pp * 4 + k][0] = (((p3 * HPL) + yc) * HPL + xc) * 128;   // BYTE offset
            s_tap[p][pp * 4 + k][1] = *(const int*)&hw2;
        }
    }
    // no barrier: wave reads only its own s_tap rows below

    // ---------------- phase B: wave-private gather, 2 rounds of 8 rows ----------------
    {
        unsigned subo = (unsigned)((lane & 7) * 16);
#pragma unroll 1
        for (int round = 0; round < 2; ++round) {
            int p = wave * 16 + round * 8 + (lane >> 3);   // this wave's rows only
            int off[12];
            int wb[12];
#pragma unroll
            for (int kk = 0; kk < 12; ++kk) {
                off[kk] = s_tap[p][kk][0];
                wb[kk]  = s_tap[p][kk][1];
            }
            __half2 acc2[4];
#pragma unroll
            for (int i = 0; i < 4; ++i) acc2[i] = __half2half2(__float2half(0.0f));
#pragma unroll
            for (int kk = 0; kk < 12; ++kk) {
                __half2 w2 = *(const __half2*)&wb[kk];
                float4 v = *(const float4*)((const char*)planes + ((unsigned)off[kk] + subo));
                union { float4 f; __half2 h[4]; } u;
                u.f = v;
#pragma unroll
                for (int i = 0; i < 4; ++i) acc2[i] = __hfma2(u.h[i], w2, acc2[i]);
            }
            *(uint4*)&lds_x[p][(lane & 7) * 8] = *(const uint4*)&acc2[0];
        }
    }
    // no barrier: wave reads only its own lds_x rows below

    // ---------------- phase C: wave-private f16 MFMA MLP, 16 points ----------------
    {
        int g = lane >> 4, c = lane & 15;
        int mrow = wave * 16 + c;
        half8 a0 = *(const half8*)(&lds_x[mrow][g * 8]);
        half8 a1 = *(const half8*)(&lds_x[mrow][32 + g * 8]);

        float o[4][4];
#pragma unroll
        for (int r = 0; r < 4; ++r)
#pragma unroll
            for (int q = 0; q < 4; ++q) o[r][q] = 0.0f;

#pragma unroll
        for (int t = 0; t < 4; ++t) {
            half8 bf0 = *(const half8*)(w1f + ((size_t)((t * 2 + 0) * 64 + lane)) * 8);
            half8 bf1 = *(const half8*)(w1f + ((size_t)((t * 2 + 1) * 64 + lane)) * 8);
            f32x4 z = {0.f, 0.f, 0.f, 0.f};
            z = __builtin_amdgcn_mfma_f32_16x16x32_f16(a0, bf0, z, 0, 0, 0);
            z = __builtin_amdgcn_mfma_f32_16x16x32_f16(a1, bf1, z, 0, 0, 0);
            float  b1s = b1f[t * 64 + lane];
            float4 w2  = *(const float4*)(w2f + (size_t)(t * 64 + lane) * 4);
#pragma unroll
            for (int r = 0; r < 4; ++r) {
                float sp = softplusf(z[r] + b1s);
                o[r][0] = fmaf(sp, w2.x, o[r][0]);
                o[r][1] = fmaf(sp, w2.y, o[r][1]);
                o[r][2] = fmaf(sp, w2.z, o[r][2]);
                o[r][3] = fmaf(sp, w2.w, o[r][3]);
            }
        }
#pragma unroll
        for (int mask = 1; mask <= 8; mask <<= 1)
#pragma unroll
            for (int r = 0; r < 4; ++r)
#pragma unroll
                for (int q = 0; q < 4; ++q) o[r][q] += __shfl_xor(o[r][q], mask, 64);

        if (c == 0) {
#pragma unroll
            for (int r = 0; r < 4; ++r) {
                int pt = blockIdx.x * BPTS + wave * 16 + g * 4 + r;
                float sig = o[r][0] + b2[0];
                float rr = sigmoidf(o[r][1] + b2[1]) * 1.002f - 0.001f;
                float gg = sigmoidf(o[r][2] + b2[2]) * 1.002f - 0.001f;
                float bb = sigmoidf(o[r][3] + b2[3]) * 1.002f - 0.001f;
                outRGBS[pt] = make_float4(rr, gg, bb, sig);
            }
        }
    }
}

// ---- merge + final march: ONE WAVE PER RAY, lane-parallel rank-merge + scan ----
#define FM_WAVES 4
__global__ __launch_bounds__(256) void final_march(
    const float* __restrict__ depths_c, const float4* __restrict__ rgbs_c,
    const float* __restrict__ depths_f, const float4* __restrict__ rgbs_f,
    const float* __restrict__ part_mn, const float* __restrict__ part_mx,
    float* __restrict__ out)
{
    __shared__ float s_dc[FM_WAVES][NC_];
    __shared__ float s_df[FM_WAVES][NI_];
    __shared__ float s_md[FM_WAVES][96];
    __shared__ float s_ms[FM_WAVES][96];
    __shared__ float s_mr[FM_WAVES][96];
    __shared__ float s_mg[FM_WAVES][96];
    __shared__ float s_mb[FM_WAVES][96];

    int wave = threadIdx.x >> 6, lane = threadIdx.x & 63;
    int ray = blockIdx.x * FM_WAVES + wave;
    float* dcp = s_dc[wave];
    float* dfp = s_df[wave];
    float* mdp = s_md[wave];
    float* msp = s_ms[wave];
    float* mrp = s_mr[wave];
    float* mgp = s_mg[wave];
    float* mbp = s_mb[wave];

    float dcv = 0.f, dfv = 0.f;
    float4 c4 = make_float4(0, 0, 0, 0), f4 = make_float4(0, 0, 0, 0);
    if (lane < NC_) {
        dcv = depths_c[ray * NC_ + lane];
        dfv = depths_f[ray * NI_ + lane];
        dcp[lane] = dcv;
        dfp[lane] = dfv;
        c4 = rgbs_c[ray * NC_ + lane];
        f4 = rgbs_f[ray * NI_ + lane];
    }
    __syncthreads();

    if (lane < NC_) {
        int cntC = 0, rankF = 0, cntCle = 0;
#pragma unroll
        for (int j = 0; j < NC_; ++j) {
            float dfj = dfp[j];
            float dcj = dcp[j];
            cntC   += (dfj < dcv) ? 1 : 0;
            rankF  += ((dfj < dfv) || (dfj == dfv && j < lane)) ? 1 : 0;
            cntCle += (dcj <= dfv) ? 1 : 0;
        }
        int posC = lane + cntC;          // stable: coarse before equal fine
        int posF = rankF + cntCle;
        mdp[posC] = dcv; msp[posC] = c4.w; mrp[posC] = c4.x; mgp[posC] = c4.y; mbp[posC] = c4.z;
        mdp[posF] = dfv; msp[posF] = f4.w; mrp[posF] = f4.x; mgp[posF] = f4.y; mbp[posF] = f4.z;
    }
    __syncthreads();

    int k0 = 2 * lane;
    int i0 = min(k0, 95), i1 = min(k0 + 1, 95), i2 = min(k0 + 2, 95);
    float d0 = mdp[i0], d1 = mdp[i1], d2 = mdp[i2];
    float sg0 = msp[i0], sg1 = msp[i1], sg2 = msp[i2];
    float r0 = mrp[i0], r1 = mrp[i1], r2 = mrp[i2];
    float g0 = mgp[i0], g1 = mgp[i1], g2 = mgp[i2];
    float bb0 = mbp[i0], bb1 = mbp[i1], bb2 = mbp[i2];

    bool v0 = (k0 < 95), v1 = (k0 + 1 < 95);
    float a0 = 0.f, a1 = 0.f, f0 = 1.f, f1 = 1.f;
    if (v0) {
        float dens = softplusf(0.5f * (sg0 + sg1) - 1.0f);
        a0 = 1.0f - __expf(-dens * (d1 - d0));
        f0 = 1.0f - a0 + 1e-10f;
    }
    if (v1) {
        float dens = softplusf(0.5f * (sg1 + sg2) - 1.0f);
        a1 = 1.0f - __expf(-dens * (d2 - d1));
        f1 = 1.0f - a1 + 1e-10f;
    }

    float pl = f0 * f1;
    float x = pl;
#pragma unroll
    for (int d = 1; d < 64; d <<= 1) {
        float t = __shfl_up(x, d, 64);
        if (lane >= d) x *= t;
    }
    float excl = __shfl_up(x, 1, 64);
    if (lane == 0) excl = 1.0f;
    float w0 = a0 * excl;
    float w1 = a1 * excl * f0;

    float accR = w0 * 0.5f * (r0 + r1) + w1 * 0.5f * (r1 + r2);
    float accG = w0 * 0.5f * (g0 + g1) + w1 * 0.5f * (g1 + g2);
    float accB = w0 * 0.5f * (bb0 + bb1) + w1 * 0.5f * (bb1 + bb2);
    float accD = w0 * 0.5f * (d0 + d1) + w1 * 0.5f * (d1 + d2);
    float accW = w0 + w1;
#pragma unroll
    for (int mask = 1; mask <= 32; mask <<= 1) {
        accR += __shfl_xor(accR, mask, 64);
        accG += __shfl_xor(accG, mask, 64);
        accB += __shfl_xor(accB, mask, 64);
        accD += __shfl_xor(accD, mask, 64);
        accW += __shfl_xor(accW, mask, 64);
    }

    // global clip bounds from 16 partials (no atomics anywhere)
    float pmn = (lane < 16) ? part_mn[lane] : INFINITY;
    float pmx = (lane < 16) ? part_mx[lane] : -INFINITY;
#pragma unroll
    for (int mask = 1; mask <= 32; mask <<= 1) {
        pmn = fminf(pmn, __shfl_xor(pmn, mask, 64));
        pmx = fmaxf(pmx, __shfl_xor(pmx, mask, 64));
    }

    if (lane == 0) {
        float q = accD / accW;
        if (!isfinite(q)) q = 0.0f;
        q = fminf(fmaxf(q, pmn), pmx);
        out[ray * 3 + 0] = accR * 2.0f - 1.0f;
        out[ray * 3 + 1] = accG * 2.0f - 1.0f;
        out[ray * 3 + 2] = accB * 2.0f - 1.0f;
        out[3 * NRAY + ray] = q;
        out[4 * NRAY + ray] = accW;
    }
}

extern "C" void kernel_launch(void* const* d_in, const int* in_sizes, int n_in,
                              void* d_out, int out_size, void* d_ws, size_t ws_size,
                              hipStream_t stream)
{
    const float* planes_tex = (const float*)d_in[0];
    const float* planes_shp = (const float*)d_in[1];
    const float* origins    = (const float*)d_in[2];
    const float* raydirs    = (const float*)d_in[3];
    const float* W1 = (const float*)d_in[4];
    const float* b1 = (const float*)d_in[5];
    const float* W2 = (const float*)d_in[6];
    const float* b2 = (const float*)d_in[7];
    const float* noise = (const float*)d_in[8];
    const float* impu  = (const float*)d_in[9];
    float* out = (float*)d_out;

    char* ws = (char*)d_ws;
    __half*         planes_cl = (__half*)ws;                          // 50,331,648 B
    __half*         w1f       = (__half*)(ws + 50331648);             // 8,192 B
    float*          w2f       = (float*)(ws + 50339840);              // 4,096 B
    float*          b1f       = (float*)(ws + 50343936);              // 1,024 B
    float*          part_mn   = (float*)(ws + 50344960);              // 64 B
    float*          part_mx   = (float*)(ws + 50345024);              // 64 B
    float*  depths_c = (float*)(ws + 50345216);                       // 1,572,864 B
    float*  depths_f = (float*)(ws + 51918080);                       // 1,572,864 B
    float4* rgbs_c   = (float4*)(ws + 53490944);                      // 6,291,456 B
    float4* rgbs_f   = (float4*)(ws + 59782400);                      // 6,291,456 B
    float*  rayod    = (float*)(ws + 66073856);                       // 262,144 B

    setup_kernel<<<dim3(TR_BLOCKS + 1 + 16 + 32), dim3(256), 0, stream>>>(
        planes_tex, planes_shp, planes_cl, W1, b1, W2, w1f, w2f, b1f, part_mn, part_mx,
        noise, origins, raydirs, rayod);

    fused_sample_mlp<false><<<dim3(NPTS / BPTS), dim3(256), 0, stream>>>(
        planes_cl, rayod, noise, nullptr, nullptr, nullptr,
        depths_c, w1f, w2f, b1f, b2, rgbs_c);

    fused_sample_mlp<true><<<dim3(NPTS / BPTS), dim3(256), 0, stream>>>(
        planes_cl, rayod, nullptr, impu, depths_c, rgbs_c,
        depths_f, w1f, w2f, b1f, b2, rgbs_f);

    final_march<<<dim3(NRAY / FM_WAVES), dim3(256), 0, stream>>>(
        depths_c, rgbs_c, depths_f, rgbs_f, part_mn, part_mx, out);
}

// Round 9
// 267.937 us; speedup vs baseline: 1.1822x; 1.0050x over previous
//
#include <hip/hip_runtime.h>
#include <hip/hip_fp16.h>
#include <math.h>

#define NRAY 8192
#define NC_  48
#define NI_  48
#define HPL  256
#define HID  64
#define NPTS (NRAY * NC_)        // 393216 points per pass
#define BPTS 64                  // points per block (proven optimum of this structure)

typedef __attribute__((ext_vector_type(8))) _Float16 half8;  // 8 fp16 (4 VGPRs)
typedef __attribute__((ext_vector_type(4))) float f32x4;

__device__ __forceinline__ float softplusf(float x) {
    return fmaxf(x, 0.0f) + __logf(1.0f + __expf(-fabsf(x)));
}
__device__ __forceinline__ float sigmoidf(float x) {
    return 1.0f / (1.0f + __expf(-x));
}

// ================= setup mega-kernel =================
// blocks [0, 3072): transpose (p in [0,12), y in [0,256)) -> fp16 channel-last interleaved.
// block 3072: weight fragment prep (fp16 W1 fragments).
// blocks 3073..3088: minmax partials from noise (no atomics).
// blocks 3089..3120: per-ray dir normalization -> rayod[ray*8] = {ox,oy,oz,dx,dy,dz,0,0}
#define TR_BLOCKS 3072
__global__ __launch_bounds__(256) void setup_kernel(
    const float* __restrict__ tex, const float* __restrict__ shp,
    __half* __restrict__ planes_cl,
    const float* __restrict__ W1, const float* __restrict__ b1, const float* __restrict__ W2,
    __half* __restrict__ w1f, float* __restrict__ w2f, float* __restrict__ b1f,
    float* __restrict__ part_mn, float* __restrict__ part_mx,
    const float* __restrict__ noise,
    const float* __restrict__ origins, const float* __restrict__ dirs,
    float* __restrict__ rayod)
{
    __shared__ __half t2[256][40];     // [x][c]; rows 80B -> 16B-aligned b128 reads, 2-way write conflict (free)
    __shared__ float smn[4], smx[4];
    int b = blockIdx.x;
    int tid = threadIdx.x;
    if (b < TR_BLOCKS) {
        int p = b >> 8;                // [0,12)
        int y = b & 255;
        const float* in = (p < 6) ? tex : shp;
        int pp    = (p < 6) ? p : p - 6;
        int choff = (p < 6) ? 0 : 32;
        const float* base = in + ((size_t)(pp * 32) * 256 + y) * 256;   // base[c*65536 + x]
        int lane6 = tid & 63;          // x-group within wave
        int cb    = (tid >> 6) * 8;    // c base: 0,8,16,24 per wave
        int x0    = lane6 * 4;
#pragma unroll
        for (int i = 0; i < 8; ++i) {
            float4 v = *(const float4*)(base + (size_t)(cb + i) * 65536 + x0);
            t2[x0 + 0][cb + i] = __float2half(v.x);
            t2[x0 + 1][cb + i] = __float2half(v.y);
            t2[x0 + 2][cb + i] = __float2half(v.z);
            t2[x0 + 3][cb + i] = __float2half(v.w);
        }
        __syncthreads();
        __half* outRow = planes_cl + ((size_t)(pp * 256 + y) * 256) * 64 + choff;
#pragma unroll
        for (int it = 0; it < 4; ++it) {
            int idx = it * 256 + tid;
            int x = idx >> 2, c8 = (idx & 3) * 8;
            *(uint4*)(outRow + (size_t)x * 64 + c8) = *(const uint4*)&t2[x][c8];
        }
    } else if (b == TR_BLOCKS) {
        int l = tid;
        if (l < 64) {
            int g = l >> 4, c = l & 15;
#pragma unroll
            for (int t = 0; t < 4; ++t) {
#pragma unroll
                for (int kb = 0; kb < 2; ++kb)
#pragma unroll
                    for (int j = 0; j < 8; ++j)
                        w1f[((t * 2 + kb) * 64 + l) * 8 + j] =
                            __float2half(W1[(kb * 32 + g * 8 + j) * HID + t * 16 + c]);
#pragma unroll
                for (int o = 0; o < 4; ++o) w2f[(t * 64 + l) * 4 + o] = W2[(t * 16 + c) * 4 + o];
                b1f[t * 64 + l] = b1[t * 16 + c];
            }
        }
    } else if (b < TR_BLOCKS + 17) {
        // minmax partials
        int bl = b - TR_BLOCKS - 1;            // [0,16)
        int gtid = bl * 256 + tid;             // [0,4096)
        float mn = INFINITY, mx = -INFINITY;
        for (int r = gtid; r < NRAY; r += 4096) {
            mn = fminf(mn, noise[r * NC_]);
            mx = fmaxf(mx, noise[r * NC_ + NC_ - 1]);
        }
#pragma unroll
        for (int mask = 1; mask <= 32; mask <<= 1) {
            mn = fminf(mn, __shfl_xor(mn, mask, 64));
            mx = fmaxf(mx, __shfl_xor(mx, mask, 64));
        }
        int wv = tid >> 6;
        if ((tid & 63) == 0) { smn[wv] = mn; smx[wv] = mx; }
        __syncthreads();
        if (tid == 0) {
#pragma unroll
            for (int i = 1; i < 4; ++i) { mn = fminf(mn, smn[i]); mx = fmaxf(mx, smx[i]); }
            const float delta = (1.0f - 0.1f) / (NC_ - 1);
            part_mn[bl] = 0.1f + mn * delta;                    // s = 0 term
            part_mx[bl] = 0.1f + delta * 47.0f + mx * delta;    // s = 47 term
        }
    } else {
        // per-ray normalized direction precompute
        int ray = (b - TR_BLOCKS - 17) * 256 + tid;             // [0,8192)
        float ox = origins[ray * 3 + 0], oy = origins[ray * 3 + 1], oz = origins[ray * 3 + 2];
        float dx = dirs[ray * 3 + 0], dy = dirs[ray * 3 + 1], dz = dirs[ray * 3 + 2];
        float invn = 1.0f / sqrtf(dx * dx + dy * dy + dz * dz);
        dx *= invn; dy *= invn; dz *= invn;
        float4 A4 = make_float4(ox, oy, oz, dx);
        float4 B4 = make_float4(dy, dz, 0.0f, 0.0f);
        *(float4*)(rayod + (size_t)ray * 8)     = A4;
        *(float4*)(rayod + (size_t)ray * 8 + 4) = B4;
    }
}

// ================= fused plane-gather + MFMA MLP (coarse & fine) =================
// Block = 64 points. WAVE-PRIVATE pipeline (no coarse barriers): each wave owns 16 points:
//   Phase A (lanes 0-47): taps for points wave*16..+16 -> s_tap rows
//   Phase B: 2 rounds; ALL 12 tap loads issued into registers before use (MLP: 12 in flight)
//   Phase C: w1f fragments hoisted to registers; MFMA MLP on rows wave*16+c
// FINE: cdf prologue is cross-wave => ONE barrier after it.
template<bool FINE>
__global__ __launch_bounds__(256, 8) void fused_sample_mlp(
    const __half* __restrict__ planes,     // (6,256,256,64) interleaved fp16
    const float* __restrict__ rayod,       // per-ray {o,dnorm} packed (8 floats)
    const float* __restrict__ noise,       // coarse only
    const float* __restrict__ impu,        // fine only
    const float* __restrict__ depths_c,    // fine only (read, per-ray rows)
    const float4* __restrict__ rgbs_c_in,  // fine only (read sigma)
    float* __restrict__ depths_out,        // write: depths_c (coarse) / depths_f (fine)
    const __half* __restrict__ w1f, const float* __restrict__ w2f,
    const float* __restrict__ b1f, const float* __restrict__ b2,
    float4* __restrict__ outRGBS)          // [point]
{
    __shared__ __half lds_x[BPTS][72];         // feature rows (fp16), stride 72 halves
    __shared__ int s_tap[BPTS][12][2];         // (byte offset, packed half2 weight)
    __shared__ float s_cdf[2][48];             // FINE: [0..45] cdf per local ray
    __shared__ float s_zm[2][48];              // FINE: [0..46] z_mid per local ray

    int tid = threadIdx.x;
    int wave = tid >> 6, lane = tid & 63;
    int r0 = (blockIdx.x * BPTS) / NC_;

    if constexpr (FINE) {
        int r1 = (blockIdx.x * BPTS + BPTS - 1) / NC_;
        if (wave <= r1 - r0) {                 // wave 0 always; wave 1 iff block spans 2 rays
            int ray = r0 + wave;
            float d = 0.f, sg = 0.f;
            if (lane < NC_) {
                d  = depths_c[ray * NC_ + lane];
                sg = rgbs_c_in[ray * NC_ + lane].w;
            }
            float dn = __shfl_down(d, 1, 64);
            float sn = __shfl_down(sg, 1, 64);
            bool iv = (lane < NC_ - 1);
            float zm = 0.5f * (d + dn);
            float alpha = 0.f, f = 1.0f;
            if (iv) {
                float dens = softplusf(0.5f * (sg + sn) - 1.0f);
                alpha = 1.0f - __expf(-dens * (dn - d));
                f = 1.0f - alpha + 1e-10f;
            }
            float x = f;
#pragma unroll
            for (int s = 1; s < 64; s <<= 1) {
                float t = __shfl_up(x, s, 64);
                if (lane >= s) x *= t;
            }
            float excl = __shfl_up(x, 1, 64);
            if (lane == 0) excl = 1.0f;
            float w = alpha * excl;
            float wprev = __shfl_up(w, 1, 64);
            float wmax;
            if (lane == 0) wmax = w;
            else if (lane == NC_ - 1) wmax = wprev;
            else wmax = fmaxf(wprev, w);
            float wmaxn = __shfl_down(wmax, 1, 64);
            float wb = 0.5f * (wmax + wmaxn) + 0.01f;
            float v = (lane >= 1 && lane <= 45) ? wb : 0.0f;
            float ssum = v;
#pragma unroll
            for (int mask = 1; mask <= 32; mask <<= 1) ssum += __shfl_xor(ssum, mask, 64);
            float pdf = v / ssum;
            float cum = pdf;
#pragma unroll
            for (int st = 1; st < 64; st <<= 1) {
                float t = __shfl_up(cum, st, 64);
                if (lane >= st) cum += t;
            }
            if (lane <= 45) s_cdf[wave][lane] = (lane == 0) ? 0.0f : cum;
            if (iv) s_zm[wave][lane] = zm;
        }
        __syncthreads();                       // the ONLY barrier (cdf is cross-wave)
    }

    // ---------------- phase A: wave-private taps (lanes 0-47: 16 points x 3 planes) --------
    if (lane < 48) {
        int p  = wave * 16 + (lane & 15);      // this wave's point rows
        int pp = lane >> 4;                    // plane 0..2
        int point = blockIdx.x * BPTS + p;
        int ray = point / NC_;
        int bIdx = ray >> 12;

        float t;
        if constexpr (!FINE) {
            int s = point - ray * NC_;
            const float delta = (1.0f - 0.1f) / (NC_ - 1);
            t = 0.1f + delta * (float)s + noise[point] * delta;
        } else {
            int ridx = ray - r0;
            float u = impu[point];
            const float* cdf = s_cdf[ridx];
            const float* zmp = s_zm[ridx];
            int lo = 0, hi = 46;
            while (lo < hi) { int mid = (lo + hi) >> 1; if (cdf[mid] > u) hi = mid; else lo = mid + 1; }
            int below = max(lo - 1, 0);
            int above = min(lo, 45);
            float c0 = cdf[below], c1 = cdf[above];
            float b0 = zmp[below], b1v = zmp[above];
            float den = c1 - c0; if (den < 1e-5f) den = 1.0f;
            t = b0 + (u - c0) / den * (b1v - b0);
        }
        if (pp == 0) depths_out[point] = t;

        const float4 A4 = *(const float4*)(rayod + (size_t)ray * 8);
        const float4 B4 = *(const float4*)(rayod + (size_t)ray * 8 + 4);
        float px = A4.x + t * A4.w;
        float py = A4.y + t * B4.x;
        float pz = A4.z + t * B4.y;

        // projections: p0:(x,y) p1:(x,z) p2:(z,x)
        float U = (pp == 2) ? pz : px;
        float V = (pp == 0) ? py : ((pp == 1) ? pz : px);
        const float inv3 = 1.0f / 3.0f;

        float gx = (U + 1.0f) * 128.0f - 0.5f;
        float gy = (V + 1.0f) * 128.0f - 0.5f;
        float fgx = floorf(gx), fgy = floorf(gy);
        int x0 = (int)fgx, y0 = (int)fgy;
        float fx = gx - fgx, fy = gy - fgy;
#pragma unroll
        for (int k = 0; k < 4; ++k) {
            int dxk = k & 1, dyk = k >> 1;
            int xi = x0 + dxk, yi = y0 + dyk;
            float w = (dxk ? fx : 1.0f - fx) * (dyk ? fy : 1.0f - fy);
            bool valid = (xi >= 0) && (xi < HPL) && (yi >= 0) && (yi < HPL);
            int xc = min(max(xi, 0), HPL - 1);
            int yc = min(max(yi, 0), HPL - 1);
            int p3 = bIdx * 3 + pp;
            __half2 hw2 = __half2half2(__float2half(valid ? w * inv3 : 0.0f));
            s_tap[p][pp * 4 + k][0] = (((p3 * HPL) + yc) * HPL + xc) * 128;   // BYTE offset
            s_tap[p][pp * 4 + k][1] = *(const int*)&hw2;
        }
    }
    // no barrier: wave reads only its own s_tap rows below

    // ---------------- phase B: wave-private gather; ALL 12 loads in flight ----------------
    {
        unsigned subo = (unsigned)((lane & 7) * 16);
#pragma unroll 1
        for (int round = 0; round < 2; ++round) {
            int p = wave * 16 + round * 8 + (lane >> 3);   // this wave's rows only
            int off[12];
#pragma unroll
            for (int kk = 0; kk < 12; ++kk) off[kk] = s_tap[p][kk][0];

            float4 v[12];                                   // 48 VGPRs of loads in flight
#pragma unroll
            for (int kk = 0; kk < 12; ++kk)
                v[kk] = *(const float4*)((const char*)planes + ((unsigned)off[kk] + subo));

            int wb[12];
#pragma unroll
            for (int kk = 0; kk < 12; ++kk) wb[kk] = s_tap[p][kk][1];

            __half2 acc2[4];
#pragma unroll
            for (int i = 0; i < 4; ++i) acc2[i] = __half2half2(__float2half(0.0f));
#pragma unroll
            for (int kk = 0; kk < 12; ++kk) {
                __half2 w2 = *(const __half2*)&wb[kk];
                union { float4 f; __half2 h[4]; } u;
                u.f = v[kk];
#pragma unroll
                for (int i = 0; i < 4; ++i) acc2[i] = __hfma2(u.h[i], w2, acc2[i]);
            }
            *(uint4*)&lds_x[p][(lane & 7) * 8] = *(const uint4*)&acc2[0];
        }
    }
    // no barrier: wave reads only its own lds_x rows below

    // ---------------- phase C: wave-private f16 MFMA MLP, 16 points ----------------
    {
        int g = lane >> 4, c = lane & 15;
        int mrow = wave * 16 + c;

        half8 wf[8];                                        // hoist all W1 fragments (32 VGPR)
#pragma unroll
        for (int t = 0; t < 4; ++t) {
            wf[2 * t]     = *(const half8*)(w1f + ((size_t)((t * 2 + 0) * 64 + lane)) * 8);
            wf[2 * t + 1] = *(const half8*)(w1f + ((size_t)((t * 2 + 1) * 64 + lane)) * 8);
        }

        half8 a0 = *(const half8*)(&lds_x[mrow][g * 8]);
        half8 a1 = *(const half8*)(&lds_x[mrow][32 + g * 8]);

        float o[4][4];
#pragma unroll
        for (int r = 0; r < 4; ++r)
#pragma unroll
            for (int q = 0; q < 4; ++q) o[r][q] = 0.0f;

#pragma unroll
        for (int t = 0; t < 4; ++t) {
            f32x4 z = {0.f, 0.f, 0.f, 0.f};
            z = __builtin_amdgcn_mfma_f32_16x16x32_f16(a0, wf[2 * t], z, 0, 0, 0);
            z = __builtin_amdgcn_mfma_f32_16x16x32_f16(a1, wf[2 * t + 1], z, 0, 0, 0);
            float  b1s = b1f[t * 64 + lane];
            float4 w2  = *(const float4*)(w2f + (size_t)(t * 64 + lane) * 4);
#pragma unroll
            for (int r = 0; r < 4; ++r) {
                float sp = softplusf(z[r] + b1s);
                o[r][0] = fmaf(sp, w2.x, o[r][0]);
                o[r][1] = fmaf(sp, w2.y, o[r][1]);
                o[r][2] = fmaf(sp, w2.z, o[r][2]);
                o[r][3] = fmaf(sp, w2.w, o[r][3]);
            }
        }
#pragma unroll
        for (int mask = 1; mask <= 8; mask <<= 1)
#pragma unroll
            for (int r = 0; r < 4; ++r)
#pragma unroll
                for (int q = 0; q < 4; ++q) o[r][q] += __shfl_xor(o[r][q], mask, 64);

        if (c == 0) {
#pragma unroll
            for (int r = 0; r < 4; ++r) {
                int pt = blockIdx.x * BPTS + wave * 16 + g * 4 + r;
                float sig = o[r][0] + b2[0];
                float rr = sigmoidf(o[r][1] + b2[1]) * 1.002f - 0.001f;
                float gg = sigmoidf(o[r][2] + b2[2]) * 1.002f - 0.001f;
                float bb = sigmoidf(o[r][3] + b2[3]) * 1.002f - 0.001f;
                outRGBS[pt] = make_float4(rr, gg, bb, sig);
            }
        }
    }
}

// ---- merge + final march: ONE WAVE PER RAY, lane-parallel rank-merge + scan ----
#define FM_WAVES 4
__global__ __launch_bounds__(256) void final_march(
    const float* __restrict__ depths_c, const float4* __restrict__ rgbs_c,
    const float* __restrict__ depths_f, const float4* __restrict__ rgbs_f,
    const float* __restrict__ part_mn, const float* __restrict__ part_mx,
    float* __restrict__ out)
{
    __shared__ float s_dc[FM_WAVES][NC_];
    __shared__ float s_df[FM_WAVES][NI_];
    __shared__ float s_md[FM_WAVES][96];
    __shared__ float s_ms[FM_WAVES][96];
    __shared__ float s_mr[FM_WAVES][96];
    __shared__ float s_mg[FM_WAVES][96];
    __shared__ float s_mb[FM_WAVES][96];

    int wave = threadIdx.x >> 6, lane = threadIdx.x & 63;
    int ray = blockIdx.x * FM_WAVES + wave;
    float* dcp = s_dc[wave];
    float* dfp = s_df[wave];
    float* mdp = s_md[wave];
    float* msp = s_ms[wave];
    float* mrp = s_mr[wave];
    float* mgp = s_mg[wave];
    float* mbp = s_mb[wave];

    float dcv = 0.f, dfv = 0.f;
    float4 c4 = make_float4(0, 0, 0, 0), f4 = make_float4(0, 0, 0, 0);
    if (lane < NC_) {
        dcv = depths_c[ray * NC_ + lane];
        dfv = depths_f[ray * NI_ + lane];
        dcp[lane] = dcv;
        dfp[lane] = dfv;
        c4 = rgbs_c[ray * NC_ + lane];
        f4 = rgbs_f[ray * NI_ + lane];
    }
    __syncthreads();

    if (lane < NC_) {
        int cntC = 0, rankF = 0, cntCle = 0;
#pragma unroll
        for (int j = 0; j < NC_; ++j) {
            float dfj = dfp[j];
            float dcj = dcp[j];
            cntC   += (dfj < dcv) ? 1 : 0;
            rankF  += ((dfj < dfv) || (dfj == dfv && j < lane)) ? 1 : 0;
            cntCle += (dcj <= dfv) ? 1 : 0;
        }
        int posC = lane + cntC;          // stable: coarse before equal fine
        int posF = rankF + cntCle;
        mdp[posC] = dcv; msp[posC] = c4.w; mrp[posC] = c4.x; mgp[posC] = c4.y; mbp[posC] = c4.z;
        mdp[posF] = dfv; msp[posF] = f4.w; mrp[posF] = f4.x; mgp[posF] = f4.y; mbp[posF] = f4.z;
    }
    __syncthreads();

    int k0 = 2 * lane;
    int i0 = min(k0, 95), i1 = min(k0 + 1, 95), i2 = min(k0 + 2, 95);
    float d0 = mdp[i0], d1 = mdp[i1], d2 = mdp[i2];
    float sg0 = msp[i0], sg1 = msp[i1], sg2 = msp[i2];
    float r0 = mrp[i0], r1 = mrp[i1], r2 = mrp[i2];
    float g0 = mgp[i0], g1 = mgp[i1], g2 = mgp[i2];
    float bb0 = mbp[i0], bb1 = mbp[i1], bb2 = mbp[i2];

    bool v0 = (k0 < 95), v1 = (k0 + 1 < 95);
    float a0 = 0.f, a1 = 0.f, f0 = 1.f, f1 = 1.f;
    if (v0) {
        float dens = softplusf(0.5f * (sg0 + sg1) - 1.0f);
        a0 = 1.0f - __expf(-dens * (d1 - d0));
        f0 = 1.0f - a0 + 1e-10f;
    }
    if (v1) {
        float dens = softplusf(0.5f * (sg1 + sg2) - 1.0f);
        a1 = 1.0f - __expf(-dens * (d2 - d1));
        f1 = 1.0f - a1 + 1e-10f;
    }

    float pl = f0 * f1;
    float x = pl;
#pragma unroll
    for (int d = 1; d < 64; d <<= 1) {
        float t = __shfl_up(x, d, 64);
        if (lane >= d) x *= t;
    }
    float excl = __shfl_up(x, 1, 64);
    if (lane == 0) excl = 1.0f;
    float w0 = a0 * excl;
    float w1 = a1 * excl * f0;

    float accR = w0 * 0.5f * (r0 + r1) + w1 * 0.5f * (r1 + r2);
    float accG = w0 * 0.5f * (g0 + g1) + w1 * 0.5f * (g1 + g2);
    float accB = w0 * 0.5f * (bb0 + bb1) + w1 * 0.5f * (bb1 + bb2);
    float accD = w0 * 0.5f * (d0 + d1) + w1 * 0.5f * (d1 + d2);
    float accW = w0 + w1;
#pragma unroll
    for (int mask = 1; mask <= 32; mask <<= 1) {
        accR += __shfl_xor(accR, mask, 64);
        accG += __shfl_xor(accG, mask, 64);
        accB += __shfl_xor(accB, mask, 64);
        accD += __shfl_xor(accD, mask, 64);
        accW += __shfl_xor(accW, mask, 64);
    }

    // global clip bounds from 16 partials (no atomics anywhere)
    float pmn = (lane < 16) ? part_mn[lane] : INFINITY;
    float pmx = (lane < 16) ? part_mx[lane] : -INFINITY;
#pragma unroll
    for (int mask = 1; mask <= 32; mask <<= 1) {
        pmn = fminf(pmn, __shfl_xor(pmn, mask, 64));
        pmx = fmaxf(pmx, __shfl_xor(pmx, mask, 64));
    }

    if (lane == 0) {
        float q = accD / accW;
        if (!isfinite(q)) q = 0.0f;
        q = fminf(fmaxf(q, pmn), pmx);
        out[ray * 3 + 0] = accR * 2.0f - 1.0f;
        out[ray * 3 + 1] = accG * 2.0f - 1.0f;
        out[ray * 3 + 2] = accB * 2.0f - 1.0f;
        out[3 * NRAY + ray] = q;
        out[4 * NRAY + ray] = accW;
    }
}

extern "C" void kernel_launch(void* const* d_in, const int* in_sizes, int n_in,
                              void* d_out, int out_size, void* d_ws, size_t ws_size,
                              hipStream_t stream)
{
    const float* planes_tex = (const float*)d_in[0];
    const float* planes_shp = (const float*)d_in[1];
    const float* origins    = (const float*)d_in[2];
    const float* raydirs    = (const float*)d_in[3];
    const float* W1 = (const float*)d_in[4];
    const float* b1 = (const float*)d_in[5];
    const float* W2 = (const float*)d_in[6];
    const float* b2 = (const float*)d_in[7];
    const float* noise = (const float*)d_in[8];
    const float* impu  = (const float*)d_in[9];
    float* out = (float*)d_out;

    char* ws = (char*)d_ws;
    __half*         planes_cl = (__half*)ws;                          // 50,331,648 B
    __half*         w1f       = (__half*)(ws + 50331648);             // 8,192 B
    float*          w2f       = (float*)(ws + 50339840);              // 4,096 B
    float*          b1f       = (float*)(ws + 50343936);              // 1,024 B
    float*          part_mn   = (float*)(ws + 50344960);              // 64 B
    float*          part_mx   = (float*)(ws + 50345024);              // 64 B
    float*  depths_c = (float*)(ws + 50345216);                       // 1,572,864 B
    float*  depths_f = (float*)(ws + 51918080);                       // 1,572,864 B
    float4* rgbs_c   = (float4*)(ws + 53490944);                      // 6,291,456 B
    float4* rgbs_f   = (float4*)(ws + 59782400);                      // 6,291,456 B
    float*  rayod    = (float*)(ws + 66073856);                       // 262,144 B

    setup_kernel<<<dim3(TR_BLOCKS + 1 + 16 + 32), dim3(256), 0, stream>>>(
        planes_tex, planes_shp, planes_cl, W1, b1, W2, w1f, w2f, b1f, part_mn, part_mx,
        noise, origins, raydirs, rayod);

    fused_sample_mlp<false><<<dim3(NPTS / BPTS), dim3(256), 0, stream>>>(
        planes_cl, rayod, noise, nullptr, nullptr, nullptr,
        depths_c, w1f, w2f, b1f, b2, rgbs_c);

    fused_sample_mlp<true><<<dim3(NPTS / BPTS), dim3(256), 0, stream>>>(
        planes_cl, rayod, nullptr, impu, depths_c, rgbs_c,
        depths_f, w1f, w2f, b1f, b2, rgbs_f);

    final_march<<<dim3(NRAY / FM_WAVES), dim3(256), 0, stream>>>(
        depths_c, rgbs_c, depths_f, rgbs_f, part_mn, part_mx, out);
}

// Round 10
// 266.818 us; speedup vs baseline: 1.1872x; 1.0042x over previous
//
#include <hip/hip_runtime.h>
#include <hip/hip_fp16.h>
#include <math.h>

#define NRAY 8192
#define NC_  48
#define NI_  48
#define HPL  256
#define HID  64
#define NPTS (NRAY * NC_)        // 393216 points per pass
#define BPTS 64                  // points per block (proven optimum of this structure)

typedef __attribute__((ext_vector_type(8))) _Float16 half8;  // 8 fp16 (4 VGPRs)
typedef __attribute__((ext_vector_type(4))) float f32x4;

__device__ __forceinline__ float softplusf(float x) {
    return fmaxf(x, 0.0f) + __logf(1.0f + __expf(-fabsf(x)));
}
__device__ __forceinline__ float sigmoidf(float x) {
    return 1.0f / (1.0f + __expf(-x));
}

// ================= setup mega-kernel =================
// blocks [0, 3072): transpose (p in [0,12), y in [0,256)) -> fp16 channel-last interleaved.
//   LDS layout [c][x] (stride 266 halves): writes 2-way (free), reads 2-way (free).
//   (old [x][40] layout: lanes wrote rows 4*lane -> bank (16*lane)%32 in {0,16} = 32-way conflict)
// block 3072: weight fragment prep (fp16 W1 fragments).
// blocks 3073..3088: minmax partials from noise (no atomics).
// blocks 3089..3120: per-ray dir normalization -> rayod[ray*8] = {ox,oy,oz,dx,dy,dz,0,0}
#define TR_BLOCKS 3072
#define TSTR 266                   // LDS row stride in halves; 133 banks/row; 133*8 % 32 = 8
__global__ __launch_bounds__(256) void setup_kernel(
    const float* __restrict__ tex, const float* __restrict__ shp,
    __half* __restrict__ planes_cl,
    const float* __restrict__ W1, const float* __restrict__ b1, const float* __restrict__ W2,
    __half* __restrict__ w1f, float* __restrict__ w2f, float* __restrict__ b1f,
    float* __restrict__ part_mn, float* __restrict__ part_mx,
    const float* __restrict__ noise,
    const float* __restrict__ origins, const float* __restrict__ dirs,
    float* __restrict__ rayod)
{
    __shared__ __align__(16) unsigned short t2t[32][TSTR];   // [c][x]
    __shared__ float smn[4], smx[4];
    int b = blockIdx.x;
    int tid = threadIdx.x;
    if (b < TR_BLOCKS) {
        int p = b >> 8;                // [0,12)
        int y = b & 255;
        const float* in = (p < 6) ? tex : shp;
        int pp    = (p < 6) ? p : p - 6;
        int choff = (p < 6) ? 0 : 32;
        const float* base = in + ((size_t)(pp * 32) * 256 + y) * 256;   // base[c*65536 + x]
        int lane6 = tid & 63;          // x-group within wave
        int cb    = (tid >> 6) * 8;    // c base: 0,8,16,24 per wave
        int x0    = lane6 * 4;
#pragma unroll
        for (int i = 0; i < 8; ++i) {
            float4 v = *(const float4*)(base + (size_t)(cb + i) * 65536 + x0);
            __half2 h01 = __floats2half2_rn(v.x, v.y);
            __half2 h23 = __floats2half2_rn(v.z, v.w);
            // two b32 LDS writes, always 4B-aligned; bank = 2*lane + const -> 2-way (free)
            *(unsigned*)&t2t[cb + i][x0]     = *(unsigned*)&h01;
            *(unsigned*)&t2t[cb + i][x0 + 2] = *(unsigned*)&h23;
        }
        __syncthreads();
        __half* outRow = planes_cl + ((size_t)(pp * 256 + y) * 256) * 64 + choff;
#pragma unroll
        for (int it = 0; it < 4; ++it) {
            int idx = it * 256 + tid;
            int x = idx >> 2, c8 = (idx & 3) * 8;
            unsigned short h[8];
#pragma unroll
            for (int k = 0; k < 8; ++k) h[k] = t2t[c8 + k][x];   // b16 reads, 2-way (free)
            uint4 o4;
            o4.x = (unsigned)h[0] | ((unsigned)h[1] << 16);
            o4.y = (unsigned)h[2] | ((unsigned)h[3] << 16);
            o4.z = (unsigned)h[4] | ((unsigned)h[5] << 16);
            o4.w = (unsigned)h[6] | ((unsigned)h[7] << 16);
            *(uint4*)(outRow + (size_t)x * 64 + c8) = o4;
        }
    } else if (b == TR_BLOCKS) {
        int l = tid;
        if (l < 64) {
            int g = l >> 4, c = l & 15;
#pragma unroll
            for (int t = 0; t < 4; ++t) {
#pragma unroll
                for (int kb = 0; kb < 2; ++kb)
#pragma unroll
                    for (int j = 0; j < 8; ++j)
                        w1f[((t * 2 + kb) * 64 + l) * 8 + j] =
                            __float2half(W1[(kb * 32 + g * 8 + j) * HID + t * 16 + c]);
#pragma unroll
                for (int o = 0; o < 4; ++o) w2f[(t * 64 + l) * 4 + o] = W2[(t * 16 + c) * 4 + o];
                b1f[t * 64 + l] = b1[t * 16 + c];
            }
        }
    } else if (b < TR_BLOCKS + 17) {
        // minmax partials
        int bl = b - TR_BLOCKS - 1;            // [0,16)
        int gtid = bl * 256 + tid;             // [0,4096)
        float mn = INFINITY, mx = -INFINITY;
        for (int r = gtid; r < NRAY; r += 4096) {
            mn = fminf(mn, noise[r * NC_]);
            mx = fmaxf(mx, noise[r * NC_ + NC_ - 1]);
        }
#pragma unroll
        for (int mask = 1; mask <= 32; mask <<= 1) {
            mn = fminf(mn, __shfl_xor(mn, mask, 64));
            mx = fmaxf(mx, __shfl_xor(mx, mask, 64));
        }
        int wv = tid >> 6;
        if ((tid & 63) == 0) { smn[wv] = mn; smx[wv] = mx; }
        __syncthreads();
        if (tid == 0) {
#pragma unroll
            for (int i = 1; i < 4; ++i) { mn = fminf(mn, smn[i]); mx = fmaxf(mx, smx[i]); }
            const float delta = (1.0f - 0.1f) / (NC_ - 1);
            part_mn[bl] = 0.1f + mn * delta;                    // s = 0 term
            part_mx[bl] = 0.1f + delta * 47.0f + mx * delta;    // s = 47 term
        }
    } else {
        // per-ray normalized direction precompute
        int ray = (b - TR_BLOCKS - 17) * 256 + tid;             // [0,8192)
        float ox = origins[ray * 3 + 0], oy = origins[ray * 3 + 1], oz = origins[ray * 3 + 2];
        float dx = dirs[ray * 3 + 0], dy = dirs[ray * 3 + 1], dz = dirs[ray * 3 + 2];
        float invn = 1.0f / sqrtf(dx * dx + dy * dy + dz * dz);
        dx *= invn; dy *= invn; dz *= invn;
        float4 A4 = make_float4(ox, oy, oz, dx);
        float4 B4 = make_float4(dy, dz, 0.0f, 0.0f);
        *(float4*)(rayod + (size_t)ray * 8)     = A4;
        *(float4*)(rayod + (size_t)ray * 8 + 4) = B4;
    }
}

// ================= fused plane-gather + MFMA MLP (coarse & fine) =================
// Block = 64 points. WAVE-PRIVATE pipeline (no coarse barriers): each wave owns 16 points.
// FINE: cdf prologue is cross-wave => ONE barrier after it.  (frozen at r9: 62.1 us/pass)
template<bool FINE>
__global__ __launch_bounds__(256, 8) void fused_sample_mlp(
    const __half* __restrict__ planes,     // (6,256,256,64) interleaved fp16
    const float* __restrict__ rayod,       // per-ray {o,dnorm} packed (8 floats)
    const float* __restrict__ noise,       // coarse only
    const float* __restrict__ impu,        // fine only
    const float* __restrict__ depths_c,    // fine only (read, per-ray rows)
    const float4* __restrict__ rgbs_c_in,  // fine only (read sigma)
    float* __restrict__ depths_out,        // write: depths_c (coarse) / depths_f (fine)
    const __half* __restrict__ w1f, const float* __restrict__ w2f,
    const float* __restrict__ b1f, const float* __restrict__ b2,
    float4* __restrict__ outRGBS)          // [point]
{
    __shared__ __half lds_x[BPTS][72];         // feature rows (fp16), stride 72 halves
    __shared__ int s_tap[BPTS][12][2];         // (byte offset, packed half2 weight)
    __shared__ float s_cdf[2][48];             // FINE: [0..45] cdf per local ray
    __shared__ float s_zm[2][48];              // FINE: [0..46] z_mid per local ray

    int tid = threadIdx.x;
    int wave = tid >> 6, lane = tid & 63;
    int r0 = (blockIdx.x * BPTS) / NC_;

    if constexpr (FINE) {
        int r1 = (blockIdx.x * BPTS + BPTS - 1) / NC_;
        if (wave <= r1 - r0) {                 // wave 0 always; wave 1 iff block spans 2 rays
            int ray = r0 + wave;
            float d = 0.f, sg = 0.f;
            if (lane < NC_) {
                d  = depths_c[ray * NC_ + lane];
                sg = rgbs_c_in[ray * NC_ + lane].w;
            }
            float dn = __shfl_down(d, 1, 64);
            float sn = __shfl_down(sg, 1, 64);
            bool iv = (lane < NC_ - 1);
            float zm = 0.5f * (d + dn);
            float alpha = 0.f, f = 1.0f;
            if (iv) {
                float dens = softplusf(0.5f * (sg + sn) - 1.0f);
                alpha = 1.0f - __expf(-dens * (dn - d));
                f = 1.0f - alpha + 1e-10f;
            }
            float x = f;
#pragma unroll
            for (int s = 1; s < 64; s <<= 1) {
                float t = __shfl_up(x, s, 64);
                if (lane >= s) x *= t;
            }
            float excl = __shfl_up(x, 1, 64);
            if (lane == 0) excl = 1.0f;
            float w = alpha * excl;
            float wprev = __shfl_up(w, 1, 64);
            float wmax;
            if (lane == 0) wmax = w;
            else if (lane == NC_ - 1) wmax = wprev;
            else wmax = fmaxf(wprev, w);
            float wmaxn = __shfl_down(wmax, 1, 64);
            float wb = 0.5f * (wmax + wmaxn) + 0.01f;
            float v = (lane >= 1 && lane <= 45) ? wb : 0.0f;
            float ssum = v;
#pragma unroll
            for (int mask = 1; mask <= 32; mask <<= 1) ssum += __shfl_xor(ssum, mask, 64);
            float pdf = v / ssum;
            float cum = pdf;
#pragma unroll
            for (int st = 1; st < 64; st <<= 1) {
                float t = __shfl_up(cum, st, 64);
                if (lane >= st) cum += t;
            }
            if (lane <= 45) s_cdf[wave][lane] = (lane == 0) ? 0.0f : cum;
            if (iv) s_zm[wave][lane] = zm;
        }
        __syncthreads();                       // the ONLY barrier (cdf is cross-wave)
    }

    // ---------------- phase A: wave-private taps (lanes 0-47: 16 points x 3 planes) --------
    if (lane < 48) {
        int p  = wave * 16 + (lane & 15);      // this wave's point rows
        int pp = lane >> 4;                    // plane 0..2
        int point = blockIdx.x * BPTS + p;
        int ray = point / NC_;
        int bIdx = ray >> 12;

        float t;
        if constexpr (!FINE) {
            int s = point - ray * NC_;
            const float delta = (1.0f - 0.1f) / (NC_ - 1);
            t = 0.1f + delta * (float)s + noise[point] * delta;
        } else {
            int ridx = ray - r0;
            float u = impu[point];
            const float* cdf = s_cdf[ridx];
            const float* zmp = s_zm[ridx];
            int lo = 0, hi = 46;
            while (lo < hi) { int mid = (lo + hi) >> 1; if (cdf[mid] > u) hi = mid; else lo = mid + 1; }
            int below = max(lo - 1, 0);
            int above = min(lo, 45);
            float c0 = cdf[below], c1 = cdf[above];
            float b0 = zmp[below], b1v = zmp[above];
            float den = c1 - c0; if (den < 1e-5f) den = 1.0f;
            t = b0 + (u - c0) / den * (b1v - b0);
        }
        if (pp == 0) depths_out[point] = t;

        const float4 A4 = *(const float4*)(rayod + (size_t)ray * 8);
        const float4 B4 = *(const float4*)(rayod + (size_t)ray * 8 + 4);
        float px = A4.x + t * A4.w;
        float py = A4.y + t * B4.x;
        float pz = A4.z + t * B4.y;

        // projections: p0:(x,y) p1:(x,z) p2:(z,x)
        float U = (pp == 2) ? pz : px;
        float V = (pp == 0) ? py : ((pp == 1) ? pz : px);
        const float inv3 = 1.0f / 3.0f;

        float gx = (U + 1.0f) * 128.0f - 0.5f;
        float gy = (V + 1.0f) * 128.0f - 0.5f;
        float fgx = floorf(gx), fgy = floorf(gy);
        int x0 = (int)fgx, y0 = (int)fgy;
        float fx = gx - fgx, fy = gy - fgy;
#pragma unroll
        for (int k = 0; k < 4; ++k) {
            int dxk = k & 1, dyk = k >> 1;
            int xi = x0 + dxk, yi = y0 + dyk;
            float w = (dxk ? fx : 1.0f - fx) * (dyk ? fy : 1.0f - fy);
            bool valid = (xi >= 0) && (xi < HPL) && (yi >= 0) && (yi < HPL);
            int xc = min(max(xi, 0), HPL - 1);
            int yc = min(max(yi, 0), HPL - 1);
            int p3 = bIdx * 3 + pp;
            __half2 hw2 = __half2half2(__float2half(valid ? w * inv3 : 0.0f));
            s_tap[p][pp * 4 + k][0] = (((p3 * HPL) + yc) * HPL + xc) * 128;   // BYTE offset
            s_tap[p][pp * 4 + k][1] = *(const int*)&hw2;
        }
    }
    // no barrier: wave reads only its own s_tap rows below

    // ---------------- phase B: wave-private gather; loads batched into registers ----------------
    {
        unsigned subo = (unsigned)((lane & 7) * 16);
#pragma unroll 1
        for (int round = 0; round < 2; ++round) {
            int p = wave * 16 + round * 8 + (lane >> 3);   // this wave's rows only
            int off[12];
#pragma unroll
            for (int kk = 0; kk < 12; ++kk) off[kk] = s_tap[p][kk][0];

            float4 v[12];
#pragma unroll
            for (int kk = 0; kk < 12; ++kk)
                v[kk] = *(const float4*)((const char*)planes + ((unsigned)off[kk] + subo));

            int wb[12];
#pragma unroll
            for (int kk = 0; kk < 12; ++kk) wb[kk] = s_tap[p][kk][1];

            __half2 acc2[4];
#pragma unroll
            for (int i = 0; i < 4; ++i) acc2[i] = __half2half2(__float2half(0.0f));
#pragma unroll
            for (int kk = 0; kk < 12; ++kk) {
                __half2 w2 = *(const __half2*)&wb[kk];
                union { float4 f; __half2 h[4]; } u;
                u.f = v[kk];
#pragma unroll
                for (int i = 0; i < 4; ++i) acc2[i] = __hfma2(u.h[i], w2, acc2[i]);
            }
            *(uint4*)&lds_x[p][(lane & 7) * 8] = *(const uint4*)&acc2[0];
        }
    }
    // no barrier: wave reads only its own lds_x rows below

    // ---------------- phase C: wave-private f16 MFMA MLP, 16 points ----------------
    {
        int g = lane >> 4, c = lane & 15;
        int mrow = wave * 16 + c;

        half8 wf[8];
#pragma unroll
        for (int t = 0; t < 4; ++t) {
            wf[2 * t]     = *(const half8*)(w1f + ((size_t)((t * 2 + 0) * 64 + lane)) * 8);
            wf[2 * t + 1] = *(const half8*)(w1f + ((size_t)((t * 2 + 1) * 64 + lane)) * 8);
        }

        half8 a0 = *(const half8*)(&lds_x[mrow][g * 8]);
        half8 a1 = *(const half8*)(&lds_x[mrow][32 + g * 8]);

        float o[4][4];
#pragma unroll
        for (int r = 0; r < 4; ++r)
#pragma unroll
            for (int q = 0; q < 4; ++q) o[r][q] = 0.0f;

#pragma unroll
        for (int t = 0; t < 4; ++t) {
            f32x4 z = {0.f, 0.f, 0.f, 0.f};
            z = __builtin_amdgcn_mfma_f32_16x16x32_f16(a0, wf[2 * t], z, 0, 0, 0);
            z = __builtin_amdgcn_mfma_f32_16x16x32_f16(a1, wf[2 * t + 1], z, 0, 0, 0);
            float  b1s = b1f[t * 64 + lane];
            float4 w2  = *(const float4*)(w2f + (size_t)(t * 64 + lane) * 4);
#pragma unroll
            for (int r = 0; r < 4; ++r) {
                float sp = softplusf(z[r] + b1s);
                o[r][0] = fmaf(sp, w2.x, o[r][0]);
                o[r][1] = fmaf(sp, w2.y, o[r][1]);
                o[r][2] = fmaf(sp, w2.z, o[r][2]);
                o[r][3] = fmaf(sp, w2.w, o[r][3]);
            }
        }
#pragma unroll
        for (int mask = 1; mask <= 8; mask <<= 1)
#pragma unroll
            for (int r = 0; r < 4; ++r)
#pragma unroll
                for (int q = 0; q < 4; ++q) o[r][q] += __shfl_xor(o[r][q], mask, 64);

        if (c == 0) {
#pragma unroll
            for (int r = 0; r < 4; ++r) {
                int pt = blockIdx.x * BPTS + wave * 16 + g * 4 + r;
                float sig = o[r][0] + b2[0];
                float rr = sigmoidf(o[r][1] + b2[1]) * 1.002f - 0.001f;
                float gg = sigmoidf(o[r][2] + b2[2]) * 1.002f - 0.001f;
                float bb = sigmoidf(o[r][3] + b2[3]) * 1.002f - 0.001f;
                outRGBS[pt] = make_float4(rr, gg, bb, sig);
            }
        }
    }
}

// ---- merge + final march: ONE WAVE PER RAY, lane-parallel rank-merge + scan ----
#define FM_WAVES 4
__global__ __launch_bounds__(256) void final_march(
    const float* __restrict__ depths_c, const float4* __restrict__ rgbs_c,
    const float* __restrict__ depths_f, const float4* __restrict__ rgbs_f,
    const float* __restrict__ part_mn, const float* __restrict__ part_mx,
    float* __restrict__ out)
{
    __shared__ float s_dc[FM_WAVES][NC_];
    __shared__ float s_df[FM_WAVES][NI_];
    __shared__ float s_md[FM_WAVES][96];
    __shared__ float s_ms[FM_WAVES][96];
    __shared__ float s_mr[FM_WAVES][96];
    __shared__ float s_mg[FM_WAVES][96];
    __shared__ float s_mb[FM_WAVES][96];

    int wave = threadIdx.x >> 6, lane = threadIdx.x & 63;
    int ray = blockIdx.x * FM_WAVES + wave;
    float* dcp = s_dc[wave];
    float* dfp = s_df[wave];
    float* mdp = s_md[wave];
    float* msp = s_ms[wave];
    float* mrp = s_mr[wave];
    float* mgp = s_mg[wave];
    float* mbp = s_mb[wave];

    float dcv = 0.f, dfv = 0.f;
    float4 c4 = make_float4(0, 0, 0, 0), f4 = make_float4(0, 0, 0, 0);
    if (lane < NC_) {
        dcv = depths_c[ray * NC_ + lane];
        dfv = depths_f[ray * NI_ + lane];
        dcp[lane] = dcv;
        dfp[lane] = dfv;
        c4 = rgbs_c[ray * NC_ + lane];
        f4 = rgbs_f[ray * NI_ + lane];
    }
    __syncthreads();

    if (lane < NC_) {
        int cntC = 0, rankF = 0, cntCle = 0;
#pragma unroll
        for (int j = 0; j < NC_; ++j) {
            float dfj = dfp[j];
            float dcj = dcp[j];
            cntC   += (dfj < dcv) ? 1 : 0;
            rankF  += ((dfj < dfv) || (dfj == dfv && j < lane)) ? 1 : 0;
            cntCle += (dcj <= dfv) ? 1 : 0;
        }
        int posC = lane + cntC;          // stable: coarse before equal fine
        int posF = rankF + cntCle;
        mdp[posC] = dcv; msp[posC] = c4.w; mrp[posC] = c4.x; mgp[posC] = c4.y; mbp[posC] = c4.z;
        mdp[posF] = dfv; msp[posF] = f4.w; mrp[posF] = f4.x; mgp[posF] = f4.y; mbp[posF] = f4.z;
    }
    __syncthreads();

    int k0 = 2 * lane;
    int i0 = min(k0, 95), i1 = min(k0 + 1, 95), i2 = min(k0 + 2, 95);
    float d0 = mdp[i0], d1 = mdp[i1], d2 = mdp[i2];
    float sg0 = msp[i0], sg1 = msp[i1], sg2 = msp[i2];
    float r0 = mrp[i0], r1 = mrp[i1], r2 = mrp[i2];
    float g0 = mgp[i0], g1 = mgp[i1], g2 = mgp[i2];
    float bb0 = mbp[i0], bb1 = mbp[i1], bb2 = mbp[i2];

    bool v0 = (k0 < 95), v1 = (k0 + 1 < 95);
    float a0 = 0.f, a1 = 0.f, f0 = 1.f, f1 = 1.f;
    if (v0) {
        float dens = softplusf(0.5f * (sg0 + sg1) - 1.0f);
        a0 = 1.0f - __expf(-dens * (d1 - d0));
        f0 = 1.0f - a0 + 1e-10f;
    }
    if (v1) {
        float dens = softplusf(0.5f * (sg1 + sg2) - 1.0f);
        a1 = 1.0f - __expf(-dens * (d2 - d1));
        f1 = 1.0f - a1 + 1e-10f;
    }

    float pl = f0 * f1;
    float x = pl;
#pragma unroll
    for (int d = 1; d < 64; d <<= 1) {
        float t = __shfl_up(x, d, 64);
        if (lane >= d) x *= t;
    }
    float excl = __shfl_up(x, 1, 64);
    if (lane == 0) excl = 1.0f;
    float w0 = a0 * excl;
    float w1 = a1 * excl * f0;

    float accR = w0 * 0.5f * (r0 + r1) + w1 * 0.5f * (r1 + r2);
    float accG = w0 * 0.5f * (g0 + g1) + w1 * 0.5f * (g1 + g2);
    float accB = w0 * 0.5f * (bb0 + bb1) + w1 * 0.5f * (bb1 + bb2);
    float accD = w0 * 0.5f * (d0 + d1) + w1 * 0.5f * (d1 + d2);
    float accW = w0 + w1;
#pragma unroll
    for (int mask = 1; mask <= 32; mask <<= 1) {
        accR += __shfl_xor(accR, mask, 64);
        accG += __shfl_xor(accG, mask, 64);
        accB += __shfl_xor(accB, mask, 64);
        accD += __shfl_xor(accD, mask, 64);
        accW += __shfl_xor(accW, mask, 64);
    }

    // global clip bounds from 16 partials (no atomics anywhere)
    float pmn = (lane < 16) ? part_mn[lane] : INFINITY;
    float pmx = (lane < 16) ? part_mx[lane] : -INFINITY;
#pragma unroll
    for (int mask = 1; mask <= 32; mask <<= 1) {
        pmn = fminf(pmn, __shfl_xor(pmn, mask, 64));
        pmx = fmaxf(pmx, __shfl_xor(pmx, mask, 64));
    }

    if (lane == 0) {
        float q = accD / accW;
        if (!isfinite(q)) q = 0.0f;
        q = fminf(fmaxf(q, pmn), pmx);
        out[ray * 3 + 0] = accR * 2.0f - 1.0f;
        out[ray * 3 + 1] = accG * 2.0f - 1.0f;
        out[ray * 3 + 2] = accB * 2.0f - 1.0f;
        out[3 * NRAY + ray] = q;
        out[4 * NRAY + ray] = accW;
    }
}

extern "C" void kernel_launch(void* const* d_in, const int* in_sizes, int n_in,
                              void* d_out, int out_size, void* d_ws, size_t ws_size,
                              hipStream_t stream)
{
    const float* planes_tex = (const float*)d_in[0];
    const float* planes_shp = (const float*)d_in[1];
    const float* origins    = (const float*)d_in[2];
    const float* raydirs    = (const float*)d_in[3];
    const float* W1 = (const float*)d_in[4];
    const float* b1 = (const float*)d_in[5];
    const float* W2 = (const float*)d_in[6];
    const float* b2 = (const float*)d_in[7];
    const float* noise = (const float*)d_in[8];
    const float* impu  = (const float*)d_in[9];
    float* out = (float*)d_out;

    char* ws = (char*)d_ws;
    __half*         planes_cl = (__half*)ws;                          // 50,331,648 B
    __half*         w1f       = (__half*)(ws + 50331648);             // 8,192 B
    float*          w2f       = (float*)(ws + 50339840);              // 4,096 B
    float*          b1f       = (float*)(ws + 50343936);              // 1,024 B
    float*          part_mn   = (float*)(ws + 50344960);              // 64 B
    float*          part_mx   = (float*)(ws + 50345024);              // 64 B
    float*  depths_c = (float*)(ws + 50345216);                       // 1,572,864 B
    float*  depths_f = (float*)(ws + 51918080);                       // 1,572,864 B
    float4* rgbs_c   = (float4*)(ws + 53490944);                      // 6,291,456 B
    float4* rgbs_f   = (float4*)(ws + 59782400);                      // 6,291,456 B
    float*  rayod    = (float*)(ws + 66073856);                       // 262,144 B

    setup_kernel<<<dim3(TR_BLOCKS + 1 + 16 + 32), dim3(256), 0, stream>>>(
        planes_tex, planes_shp, planes_cl, W1, b1, W2, w1f, w2f, b1f, part_mn, part_mx,
        noise, origins, raydirs, rayod);

    fused_sample_mlp<false><<<dim3(NPTS / BPTS), dim3(256), 0, stream>>>(
        planes_cl, rayod, noise, nullptr, nullptr, nullptr,
        depths_c, w1f, w2f, b1f, b2, rgbs_c);

    fused_sample_mlp<true><<<dim3(NPTS / BPTS), dim3(256), 0, stream>>>(
        planes_cl, rayod, nullptr, impu, depths_c, rgbs_c,
        depths_f, w1f, w2f, b1f, b2, rgbs_f);

    final_march<<<dim3(NRAY / FM_WAVES), dim3(256), 0, stream>>>(
        depths_c, rgbs_c, depths_f, rgbs_f, part_mn, part_mx, out);
}